// Round 1
// baseline (9502.914 us; speedup 1.0000x reference)
//
#include <hip/hip_runtime.h>
#include <cstdint>
#include <cstddef>

// Problem constants (from reference)
#define NATOM 262144
#define MEDGE 1048576
#define NCRY  32768
// ORIG=200, AF=64, NF=32, GH=16, H=128, NG=3

__device__ __forceinline__ float4 ld4(const float* p){ return *reinterpret_cast<const float4*>(p); }

__device__ __forceinline__ float softplusf_(float x){
  // stable logaddexp(x, 0)
  return fmaxf(x, 0.0f) + log1pf(expf(-fabsf(x)));
}
__device__ __forceinline__ float sigmoidf_(float x){ return 1.0f/(1.0f+expf(-x)); }

// monotonic float<->uint key for atomicMax-based segment max
__device__ __forceinline__ unsigned fkey(float x){
  unsigned b = __float_as_uint(x);
  return (b & 0x80000000u) ? ~b : (b | 0x80000000u);
}
__device__ __forceinline__ float fkeyinv(unsigned k){
  unsigned b = (k & 0x80000000u) ? (k & 0x7fffffffu) : ~k;
  return __uint_as_float(b);
}

// ---------------------------------------------------------------- counts
__global__ __launch_bounds__(256) void cnt_kernel(const int* __restrict__ sidx, float* __restrict__ cnt){
  for (int m = blockIdx.x*256 + threadIdx.x; m < MEDGE; m += gridDim.x*256)
    atomicAdd(&cnt[sidx[m]], 1.0f);
}
__global__ __launch_bounds__(256) void recip_kernel(float* __restrict__ cnt){
  int n = blockIdx.x*256 + threadIdx.x;
  if (n < NATOM) cnt[n] = 1.0f / fmaxf(cnt[n], 1.0f);
}

// ---------------------------------------------------------------- embedding: atom = orig @ embW + embB
// block 256: 16 rows x 16 colgroups(4) per chunk; W (200x64) in LDS
__global__ __launch_bounds__(256) void embed_kernel(const float* __restrict__ orig,
                                                    const float* __restrict__ W,
                                                    const float* __restrict__ b,
                                                    float* __restrict__ atom){
  __shared__ float Wl[200*64];     // 51.2 KB
  __shared__ float rb[200][16];    // 12.8 KB, transposed row tile
  int t = threadIdx.x;
  for (int j = t; j < 200*16; j += 256){         // float4 tiles of W
    int k = j >> 4, c4 = j & 15;
    *(float4*)&Wl[k*64 + c4*4] = ld4(W + k*64 + c4*4);
  }
  int cg = t & 15, r = t >> 4;
  float4 bias = ld4(b + cg*4);
  for (int chunk = blockIdx.x; chunk < NATOM/16; chunk += gridDim.x){
    int n0 = chunk*16;
    __syncthreads();
    for (int j = t; j < 50*16; j += 256){        // 16 rows x 50 float4
      int rr = j & 15, c = j >> 4;
      float4 v = ld4(orig + (size_t)(n0+rr)*200 + c*4);
      int k = c*4;
      rb[k][rr]=v.x; rb[k+1][rr]=v.y; rb[k+2][rr]=v.z; rb[k+3][rr]=v.w;
    }
    __syncthreads();
    float4 acc = bias;
    #pragma unroll 4
    for (int k = 0; k < 200; ++k){
      float a = rb[k][r];
      float4 w = *(float4*)&Wl[k*64 + cg*4];
      acc.x += a*w.x; acc.y += a*w.y; acc.z += a*w.z; acc.w += a*w.w;
    }
    *(float4*)&atom[(size_t)(n0+r)*64 + cg*4] = acc;
  }
}

// ---------------------------------------------------------------- edge GEMM (filt|core fused), 2 passes
// PASS 0: accumulate per-col sum/sumsq of preactivation (incl. bias)
// PASS 1: recompute, apply BN + sigmoid/softplus, s=f*c, scatter-add into meanacc[self]
template<int PASS>
__global__ __launch_bounds__(512) void edge_kernel(const float* __restrict__ atom,
                                                   const float* __restrict__ nbr_fea,
                                                   const int* __restrict__ sidx,
                                                   const int* __restrict__ nidx,
                                                   const float* __restrict__ Wf,
                                                   const float* __restrict__ Wc,
                                                   const float* __restrict__ bf,
                                                   const float* __restrict__ bc,
                                                   const float* __restrict__ scale,
                                                   const float* __restrict__ shift,
                                                   float* __restrict__ statsum,
                                                   float* __restrict__ statsq,
                                                   float* __restrict__ meanacc){
  __shared__ float Wl[160*128];   // 80 KB  (cols 0..63 = filt, 64..127 = core)
  __shared__ float xb[160][64];   // 40 KB  transposed x tile, 64 edges
  __shared__ int esi[64], eni[64];
  int t = threadIdx.x;
  // stage fused W
  for (int j = t; j < 160*32; j += 512){
    int k = j >> 5, c4 = j & 31;
    float4 v = (c4 < 16) ? ld4(Wf + k*64 + c4*4) : ld4(Wc + k*64 + (c4-16)*4);
    *(float4*)&Wl[k*128 + c4*4] = v;
  }
  int cg = t & 31, eg = t >> 5;          // cg: colgroup(4), eg: edgegroup(4)
  float bias[4], scv[4], shv[4];
  {
    float4 bb = (cg < 16) ? ld4(bf + cg*4) : ld4(bc + cg*4 - 64);
    bias[0]=bb.x; bias[1]=bb.y; bias[2]=bb.z; bias[3]=bb.w;
  }
  if (PASS == 1){
    float4 s4 = ld4(scale + cg*4), h4 = ld4(shift + cg*4);
    scv[0]=s4.x; scv[1]=s4.y; scv[2]=s4.z; scv[3]=s4.w;
    shv[0]=h4.x; shv[1]=h4.y; shv[2]=h4.z; shv[3]=h4.w;
  }
  float ssum[4] = {0,0,0,0}, ssq[4] = {0,0,0,0};

  for (int chunk = blockIdx.x; chunk < MEDGE/64; chunk += gridDim.x){
    int e0 = chunk*64;
    __syncthreads();
    if (t < 64) esi[t] = sidx[e0 + t];
    else if (t < 128) eni[t-64] = nidx[e0 + t - 64];
    __syncthreads();
    // gather x = [atom[self](64) | atom[nbr](64) | nbr_fea(32)] transposed into xb[k][e]
    for (int j = t; j < 2560; j += 512){
      int e = j & 63, c = j >> 6;   // c in 0..39 (float4 index along k)
      float4 v;
      if (c < 16)      v = ld4(atom + (size_t)esi[e]*64 + c*4);
      else if (c < 32) v = ld4(atom + (size_t)eni[e]*64 + (c-16)*4);
      else             v = ld4(nbr_fea + (size_t)(e0+e)*32 + (c-32)*4);
      int k = c*4;
      xb[k][e]=v.x; xb[k+1][e]=v.y; xb[k+2][e]=v.z; xb[k+3][e]=v.w;
    }
    __syncthreads();
    float acc[4][4];
    #pragma unroll
    for (int a=0;a<4;a++)
      #pragma unroll
      for (int q=0;q<4;q++) acc[a][q] = bias[q];
    #pragma unroll 4
    for (int k = 0; k < 160; ++k){
      float4 xv = *(float4*)&xb[k][eg*4];
      float4 wv = *(float4*)&Wl[k*128 + cg*4];
      acc[0][0]+=xv.x*wv.x; acc[0][1]+=xv.x*wv.y; acc[0][2]+=xv.x*wv.z; acc[0][3]+=xv.x*wv.w;
      acc[1][0]+=xv.y*wv.x; acc[1][1]+=xv.y*wv.y; acc[1][2]+=xv.y*wv.z; acc[1][3]+=xv.y*wv.w;
      acc[2][0]+=xv.z*wv.x; acc[2][1]+=xv.z*wv.y; acc[2][2]+=xv.z*wv.z; acc[2][3]+=xv.z*wv.w;
      acc[3][0]+=xv.w*wv.x; acc[3][1]+=xv.w*wv.y; acc[3][2]+=xv.w*wv.z; acc[3][3]+=xv.w*wv.w;
    }
    if (PASS == 0){
      #pragma unroll
      for (int a=0;a<4;a++)
        #pragma unroll
        for (int q=0;q<4;q++){ float y = acc[a][q]; ssum[q]+=y; ssq[q]+=y*y; }
    } else {
      #pragma unroll
      for (int a=0;a<4;a++){
        float act[4];
        #pragma unroll
        for (int q=0;q<4;q++){
          float y = acc[a][q]*scv[q] + shv[q];
          act[q] = (cg < 16) ? sigmoidf_(y) : softplusf_(y);
        }
        float p0 = __shfl_xor(act[0], 16);
        float p1 = __shfl_xor(act[1], 16);
        float p2 = __shfl_xor(act[2], 16);
        float p3 = __shfl_xor(act[3], 16);
        if (cg < 16){
          float* dst = meanacc + (size_t)esi[eg*4+a]*64 + cg*4;
          atomicAdd(dst+0, act[0]*p0);
          atomicAdd(dst+1, act[1]*p1);
          atomicAdd(dst+2, act[2]*p2);
          atomicAdd(dst+3, act[3]*p3);
        }
      }
    }
  }
  if (PASS == 0){
    __syncthreads();
    float* red = &xb[0][0];   // reuse as scratch: 512*8 floats
    #pragma unroll
    for (int q=0;q<4;q++){ red[t*8+q] = ssum[q]; red[t*8+4+q] = ssq[q]; }
    __syncthreads();
    if (t < 128){
      int cgj = t >> 2, q = t & 3;
      float s = 0.f, sq = 0.f;
      for (int egi = 0; egi < 16; ++egi){
        int tt = egi*32 + cgj;
        s  += red[tt*8 + q];
        sq += red[tt*8 + 4 + q];
      }
      atomicAdd(&statsum[t], s);
      atomicAdd(&statsq[t], sq);
    }
  }
}

// ---------------------------------------------------------------- BN finalize: scale/shift from stats
__global__ void bnfin_kernel(int nf, float invcnt,
                             const float* __restrict__ sum, const float* __restrict__ sq,
                             const float* __restrict__ g, const float* __restrict__ b,
                             float* __restrict__ scale, float* __restrict__ shift){
  int j = threadIdx.x;
  if (j < nf){
    float m = sum[j]*invcnt;
    float v = fmaxf(sq[j]*invcnt - m*m, 0.0f);
    float is = rsqrtf(v + 1e-5f);
    float s = g[j]*is;
    scale[j] = s;
    shift[j] = b[j] - m*s;
  }
}

// ---------------------------------------------------------------- mean = meanacc * recip, + stats over N
__global__ __launch_bounds__(256) void meanbn_stats(const float* __restrict__ recip,
                                                    float* __restrict__ meanacc,
                                                    float* __restrict__ sum, float* __restrict__ sq){
  int t = threadIdx.x;
  float s = 0.f, q = 0.f;
  for (size_t idx = (size_t)blockIdx.x*256 + t; idx < (size_t)NATOM*64; idx += (size_t)gridDim.x*256){
    int n = (int)(idx >> 6);
    float v = meanacc[idx]*recip[n];
    meanacc[idx] = v;
    s += v; q += v*v;
  }
  __shared__ float red[256][2];
  red[t][0]=s; red[t][1]=q;
  __syncthreads();
  if (t < 64){
    for (int i=1;i<4;i++){ s += red[t+64*i][0]; q += red[t+64*i][1]; }
    atomicAdd(&sum[t], s);
    atomicAdd(&sq[t], q);
  }
}

__global__ __launch_bounds__(256) void atom_update(float* __restrict__ atom,
                                                   const float* __restrict__ meanv,
                                                   const float* __restrict__ scale,
                                                   const float* __restrict__ shift){
  for (size_t idx = (size_t)blockIdx.x*256 + threadIdx.x; idx < (size_t)NATOM*64; idx += (size_t)gridDim.x*256){
    int j = (int)(idx & 63);
    atom[idx] = softplusf_(atom[idx] + meanv[idx]*scale[j] + shift[j]);
  }
}

// ---------------------------------------------------------------- gate MLP
__device__ __forceinline__ void gate_hidden(const float* __restrict__ atom, const float* Wl,
                                            const float* __restrict__ b1, int n, float* h){
  #pragma unroll
  for (int c=0;c<16;c++) h[c] = b1[c];
  #pragma unroll
  for (int k4=0;k4<16;k4++){
    float4 a = ld4(atom + (size_t)n*64 + k4*4);
    float av[4] = {a.x, a.y, a.z, a.w};
    #pragma unroll
    for (int q=0;q<4;q++){
      #pragma unroll
      for (int c=0;c<16;c++) h[c] += av[q]*Wl[(k4*4+q)*16 + c];
    }
  }
}

__global__ __launch_bounds__(256) void gate_stats(const float* __restrict__ atom,
                                                  const float* __restrict__ W1, const float* __restrict__ b1,
                                                  float* __restrict__ sum, float* __restrict__ sq){
  __shared__ float Wl[64*16];
  int t = threadIdx.x;
  *(float4*)&Wl[t*4] = ld4(W1 + t*4);
  __syncthreads();
  int n = blockIdx.x*256 + t;
  float h[16];
  gate_hidden(atom, Wl, b1, n, h);
  int lane = t & 63;
  #pragma unroll
  for (int c=0;c<16;c++){
    float v = h[c], v2 = h[c]*h[c];
    for (int off=32; off; off >>= 1){ v += __shfl_down(v, off); v2 += __shfl_down(v2, off); }
    if (lane == 0){ atomicAdd(&sum[c], v); atomicAdd(&sq[c], v2); }
  }
}

__global__ __launch_bounds__(256) void gate_apply(const float* __restrict__ atom,
                                                  const float* __restrict__ W1, const float* __restrict__ b1,
                                                  const float* __restrict__ scale, const float* __restrict__ shift,
                                                  const float* __restrict__ W2, const float* __restrict__ b2,
                                                  const int* __restrict__ cry,
                                                  float* __restrict__ gate, unsigned* __restrict__ gmaxk){
  __shared__ float Wl[64*16];
  int t = threadIdx.x;
  *(float4*)&Wl[t*4] = ld4(W1 + t*4);
  __syncthreads();
  int n = blockIdx.x*256 + t;
  float h[16];
  gate_hidden(atom, Wl, b1, n, h);
  float g = b2[0];
  #pragma unroll
  for (int c=0;c<16;c++){
    float y = fmaxf(h[c]*scale[c] + shift[c], 0.0f);
    g += y * W2[c];
  }
  gate[n] = g;
  atomicMax(&gmaxk[cry[n]], fkey(g));
}

__global__ __launch_bounds__(256) void gate_exp(float* __restrict__ gate,
                                                const float* __restrict__ aw,
                                                const int* __restrict__ cry,
                                                const unsigned* __restrict__ gmaxk,
                                                float* __restrict__ gsum){
  int n = blockIdx.x*256 + threadIdx.x;
  if (n < NATOM){
    int c = cry[n];
    float w = aw[n]*expf(gate[n] - fkeyinv(gmaxk[c]));
    gate[n] = w;
    atomicAdd(&gsum[c], w);
  }
}

__global__ __launch_bounds__(256) void crys_acc(const float* __restrict__ gate,
                                                const float* __restrict__ gsum,
                                                const int* __restrict__ cry,
                                                const float* __restrict__ atom,
                                                float* __restrict__ crys){
  for (size_t idx = (size_t)blockIdx.x*256 + threadIdx.x; idx < (size_t)NATOM*64; idx += (size_t)gridDim.x*256){
    int n = (int)(idx >> 6), j = (int)(idx & 63);
    int c = cry[n];
    float wn = gate[n] / (gsum[c] + 1e-13f);
    atomicAdd(&crys[(size_t)c*64 + j], wn*atom[idx]);
  }
}

// ---------------------------------------------------------------- fc head: hid = crys @ fcW + fcb (+ stats over C)
__global__ __launch_bounds__(512) void fc_stats(const float* __restrict__ crys,
                                                const float* __restrict__ fcW, const float* __restrict__ fcb,
                                                float* __restrict__ hid,
                                                float* __restrict__ statsum, float* __restrict__ statsq){
  __shared__ float Wl[64*128];  // 32 KB
  __shared__ float cb[64][16];  // 4 KB
  int t = threadIdx.x;
  for (int j = t; j < 64*32; j += 512)
    *(float4*)&Wl[j*4] = ld4(fcW + j*4);
  int cg = t & 31, cr = t >> 5;   // 32 colgroups x 16 crystals
  float4 bias = ld4(fcb + cg*4);
  float ssum[4] = {0,0,0,0}, ssq[4] = {0,0,0,0};
  for (int chunk = blockIdx.x; chunk < NCRY/16; chunk += gridDim.x){
    int c0 = chunk*16;
    __syncthreads();
    for (int j = t; j < 256; j += 512){
      int rr = j & 15, c = j >> 4;
      float4 v = ld4(crys + (size_t)(c0+rr)*64 + c*4);
      int k = c*4;
      cb[k][rr]=v.x; cb[k+1][rr]=v.y; cb[k+2][rr]=v.z; cb[k+3][rr]=v.w;
    }
    __syncthreads();
    float4 acc = bias;
    #pragma unroll 4
    for (int k=0;k<64;k++){
      float a = cb[k][cr];
      float4 w = *(float4*)&Wl[k*128 + cg*4];
      acc.x += a*w.x; acc.y += a*w.y; acc.z += a*w.z; acc.w += a*w.w;
    }
    *(float4*)&hid[(size_t)(c0+cr)*128 + cg*4] = acc;
    ssum[0]+=acc.x; ssum[1]+=acc.y; ssum[2]+=acc.z; ssum[3]+=acc.w;
    ssq[0]+=acc.x*acc.x; ssq[1]+=acc.y*acc.y; ssq[2]+=acc.z*acc.z; ssq[3]+=acc.w*acc.w;
  }
  __syncthreads();
  float* red = Wl;  // reuse as scratch
  #pragma unroll
  for (int q=0;q<4;q++){ red[t*8+q] = ssum[q]; red[t*8+4+q] = ssq[q]; }
  __syncthreads();
  if (t < 128){
    int cgj = t >> 2, q = t & 3;
    float s = 0.f, sq = 0.f;
    for (int cri=0; cri<16; cri++){
      int tt = cri*32 + cgj;
      s  += red[tt*8+q];
      sq += red[tt*8+4+q];
    }
    atomicAdd(&statsum[t], s);
    atomicAdd(&statsq[t], sq);
  }
}

__global__ __launch_bounds__(256) void out_kernel(const float* __restrict__ hid,
                                                  const float* __restrict__ scale, const float* __restrict__ shift,
                                                  const float* __restrict__ outW, const float* __restrict__ outb,
                                                  float* __restrict__ out){
  int c = blockIdx.x*4 + (threadIdx.x >> 6);
  int l = threadIdx.x & 63;
  float v = softplusf_(hid[(size_t)c*128 + l]*scale[l] + shift[l])*outW[l]
          + softplusf_(hid[(size_t)c*128 + 64 + l]*scale[64+l] + shift[64+l])*outW[64+l];
  for (int off=32; off; off >>= 1) v += __shfl_down(v, off);
  if (l == 0) out[c] = v + outb[0];
}

// ---------------------------------------------------------------- launch
extern "C" void kernel_launch(void* const* d_in, const int* in_sizes, int n_in,
                              void* d_out, int out_size, void* d_ws, size_t ws_size,
                              hipStream_t stream){
  const float* aw    = (const float*)d_in[0];
  const float* orig  = (const float*)d_in[1];
  const float* nbr   = (const float*)d_in[2];
  const int*   sidx  = (const int*)d_in[3];
  const int*   nidx  = (const int*)d_in[4];
  const int*   cry   = (const int*)d_in[5];
  const float* embW  = (const float*)d_in[6];
  const float* embB  = (const float*)d_in[7];
  const float* filtW = (const float*)d_in[8];
  const float* filtB = (const float*)d_in[9];
  const float* coreW = (const float*)d_in[10];
  const float* coreB = (const float*)d_in[11];
  const float* bnfg  = (const float*)d_in[12];
  const float* bnfb  = (const float*)d_in[13];
  const float* bncg  = (const float*)d_in[14];
  const float* bncb  = (const float*)d_in[15];
  const float* bnog  = (const float*)d_in[16];
  const float* bnob  = (const float*)d_in[17];
  const float* gW1   = (const float*)d_in[18];
  const float* gb1   = (const float*)d_in[19];
  const float* gbng  = (const float*)d_in[20];
  const float* gbnb  = (const float*)d_in[21];
  const float* gW2   = (const float*)d_in[22];
  const float* gb2   = (const float*)d_in[23];
  const float* fcW   = (const float*)d_in[24];
  const float* fcb   = (const float*)d_in[25];
  const float* fcbng = (const float*)d_in[26];
  const float* fcbnb = (const float*)d_in[27];
  const float* outW  = (const float*)d_in[28];
  const float* outb  = (const float*)d_in[29];
  float* out = (float*)d_out;

  float* ws      = (float*)d_ws;
  float* atom    = ws;                              // N*64
  float* meanacc = atom    + (size_t)NATOM*64;      // N*64
  float* cnt     = meanacc + (size_t)NATOM*64;      // N
  float* gate    = cnt     + NATOM;                 // N
  float* gmaxk   = gate    + NATOM;                 // C (unsigned keys)
  float* gsum    = gmaxk   + NCRY;                  // C
  float* crys    = gsum    + NCRY;                  // C*64
  float* hid     = crys    + (size_t)NCRY*64;       // C*128
  float* stats   = hid     + (size_t)NCRY*128;      // 256
  float* scale   = stats   + 256;                   // 128
  float* shift   = scale   + 128;                   // 128
  (void)in_sizes; (void)n_in; (void)out_size; (void)ws_size;

  // counts
  hipMemsetAsync(cnt, 0, NATOM*sizeof(float), stream);
  cnt_kernel<<<2048, 256, 0, stream>>>(sidx, cnt);
  recip_kernel<<<NATOM/256, 256, 0, stream>>>(cnt);

  // embedding
  embed_kernel<<<2048, 256, 0, stream>>>(orig, embW, embB, atom);

  // message-passing layers
  for (int i = 0; i < 3; ++i){
    const float* Wf = filtW + (size_t)i*160*64;
    const float* Wc = coreW + (size_t)i*160*64;
    const float* bf = filtB + i*64;
    const float* bc = coreB + i*64;
    hipMemsetAsync(stats, 0, 256*sizeof(float), stream);
    edge_kernel<0><<<2048, 512, 0, stream>>>(atom, nbr, sidx, nidx, Wf, Wc, bf, bc,
                                             nullptr, nullptr, stats, stats+128, nullptr);
    bnfin_kernel<<<1, 64, 0, stream>>>(64, 1.0f/MEDGE, stats,    stats+128,    bnfg+i*64, bnfb+i*64, scale,    shift);
    bnfin_kernel<<<1, 64, 0, stream>>>(64, 1.0f/MEDGE, stats+64, stats+128+64, bncg+i*64, bncb+i*64, scale+64, shift+64);
    hipMemsetAsync(meanacc, 0, (size_t)NATOM*64*sizeof(float), stream);
    edge_kernel<1><<<2048, 512, 0, stream>>>(atom, nbr, sidx, nidx, Wf, Wc, bf, bc,
                                             scale, shift, nullptr, nullptr, meanacc);
    hipMemsetAsync(stats, 0, 128*sizeof(float), stream);
    meanbn_stats<<<2048, 256, 0, stream>>>(cnt, meanacc, stats, stats+64);
    bnfin_kernel<<<1, 64, 0, stream>>>(64, 1.0f/NATOM, stats, stats+64, bnog+i*64, bnob+i*64, scale, shift);
    atom_update<<<2048, 256, 0, stream>>>(atom, meanacc, scale, shift);
  }

  // gate MLP + BN
  hipMemsetAsync(stats, 0, 32*sizeof(float), stream);
  gate_stats<<<NATOM/256, 256, 0, stream>>>(atom, gW1, gb1, stats, stats+16);
  bnfin_kernel<<<1, 16, 0, stream>>>(16, 1.0f/NATOM, stats, stats+16, gbng, gbnb, scale, shift);
  hipMemsetAsync(gmaxk, 0, NCRY*sizeof(unsigned), stream);
  gate_apply<<<NATOM/256, 256, 0, stream>>>(atom, gW1, gb1, scale, shift, gW2, gb2, cry, gate, (unsigned*)gmaxk);
  hipMemsetAsync(gsum, 0, NCRY*sizeof(float), stream);
  gate_exp<<<NATOM/256, 256, 0, stream>>>(gate, aw, cry, (const unsigned*)gmaxk, gsum);
  hipMemsetAsync(crys, 0, (size_t)NCRY*64*sizeof(float), stream);
  crys_acc<<<4096, 256, 0, stream>>>(gate, gsum, cry, atom, crys);

  // fc head
  hipMemsetAsync(stats, 0, 256*sizeof(float), stream);
  fc_stats<<<1024, 512, 0, stream>>>(crys, fcW, fcb, hid, stats, stats+128);
  bnfin_kernel<<<1, 128, 0, stream>>>(128, 1.0f/NCRY, stats, stats+128, fcbng, fcbnb, scale, shift);
  out_kernel<<<NCRY/4, 256, 0, stream>>>(hid, scale, shift, outW, outb, out);
}

// Round 2
// 3931.311 us; speedup vs baseline: 2.4172x; 2.4172x over previous
//
#include <hip/hip_runtime.h>
#include <cstdint>
#include <cstddef>

// Problem constants (from reference)
#define NATOM 262144
#define MEDGE 1048576
#define NCRY  32768
// ORIG=200, AF=64, NF=32, GH=16, H=128, NG=3

typedef __attribute__((ext_vector_type(8))) short short8v;   // 8 bf16 (4 VGPR)
typedef __attribute__((ext_vector_type(4))) float f32x4;     // MFMA acc

__device__ __forceinline__ float4 ld4(const float* p){ return *reinterpret_cast<const float4*>(p); }

__device__ __forceinline__ float softplusf_(float x){
  return fmaxf(x, 0.0f) + log1pf(expf(-fabsf(x)));
}
__device__ __forceinline__ float sigmoidf_(float x){ return 1.0f/(1.0f+expf(-x)); }

__device__ __forceinline__ unsigned short rne_bf16(float f){
  unsigned u = __float_as_uint(f);
  unsigned r = u + 0x7FFFu + ((u >> 16) & 1u);
  return (unsigned short)(r >> 16);
}

// monotonic float<->uint key for atomicMax-based segment max
__device__ __forceinline__ unsigned fkey(float x){
  unsigned b = __float_as_uint(x);
  return (b & 0x80000000u) ? ~b : (b | 0x80000000u);
}
__device__ __forceinline__ float fkeyinv(unsigned k){
  unsigned b = (k & 0x80000000u) ? (k & 0x7fffffffu) : ~k;
  return __uint_as_float(b);
}

// ---------------------------------------------------------------- counts
__global__ __launch_bounds__(256) void cnt_kernel(const int* __restrict__ sidx, float* __restrict__ cnt){
  for (int m = blockIdx.x*256 + threadIdx.x; m < MEDGE; m += gridDim.x*256)
    atomicAdd(&cnt[sidx[m]], 1.0f);
}
__global__ __launch_bounds__(256) void recip_kernel(float* __restrict__ cnt){
  int n = blockIdx.x*256 + threadIdx.x;
  if (n < NATOM) cnt[n] = 1.0f / fmaxf(cnt[n], 1.0f);
}

// ---------------------------------------------------------------- embedding: atom = orig @ embW + embB
__global__ __launch_bounds__(256) void embed_kernel(const float* __restrict__ orig,
                                                    const float* __restrict__ W,
                                                    const float* __restrict__ b,
                                                    float* __restrict__ atom){
  __shared__ float Wl[200*64];     // 51.2 KB
  __shared__ float rb[200][16];    // 12.8 KB, transposed row tile
  int t = threadIdx.x;
  for (int j = t; j < 200*16; j += 256){
    int k = j >> 4, c4 = j & 15;
    *(float4*)&Wl[k*64 + c4*4] = ld4(W + k*64 + c4*4);
  }
  int cg = t & 15, r = t >> 4;
  float4 bias = ld4(b + cg*4);
  for (int chunk = blockIdx.x; chunk < NATOM/16; chunk += gridDim.x){
    int n0 = chunk*16;
    __syncthreads();
    for (int j = t; j < 50*16; j += 256){
      int rr = j & 15, c = j >> 4;
      float4 v = ld4(orig + (size_t)(n0+rr)*200 + c*4);
      int k = c*4;
      rb[k][rr]=v.x; rb[k+1][rr]=v.y; rb[k+2][rr]=v.z; rb[k+3][rr]=v.w;
    }
    __syncthreads();
    float4 acc = bias;
    #pragma unroll 4
    for (int k = 0; k < 200; ++k){
      float a = rb[k][r];
      float4 w = *(float4*)&Wl[k*64 + cg*4];
      acc.x += a*w.x; acc.y += a*w.y; acc.z += a*w.z; acc.w += a*w.w;
    }
    *(float4*)&atom[(size_t)(n0+r)*64 + cg*4] = acc;
  }
}

// ---------------------------------------------------------------- W prep: fused+transposed+split-bf16
// Wth/Wtl: [layer][col(128)][k(160)] bf16, col<64 = filt, col>=64 = core
__global__ __launch_bounds__(256) void wprep(const float* __restrict__ filtW, const float* __restrict__ coreW,
                                             short* __restrict__ Wth, short* __restrict__ Wtl){
  int idx = blockIdx.x*256 + threadIdx.x;   // 3*128*160 = 61440
  if (idx >= 3*128*160) return;
  int k = idx % 160; int rest = idx / 160; int c = rest & 127; int layer = rest >> 7;
  float w = (c < 64) ? filtW[((size_t)layer*160 + k)*64 + c] : coreW[((size_t)layer*160 + k)*64 + (c-64)];
  unsigned u = __float_as_uint(w);
  unsigned h = u & 0xFFFF0000u;
  Wth[idx] = (short)(h >> 16);
  Wtl[idx] = (short)rne_bf16(w - __uint_as_float(h));
}

// ---------------------------------------------------------------- edge GEMM via split-bf16 MFMA
// x = [atom[self] | atom[nbr] | nbr_fea] (160), split x=xh+xl, W=Wh+Wl
// acc = xh*Wh + xl*Wh + xh*Wl  (error ~2^-16, fp32-grade)
// PASS0: per-col sum/sumsq of preact (incl bias).  PASS1: BN+act, s=f*c, scatter.
#define ROWB 656   // 328 bf16: hi[0..160) at bytes [0,320), lo at [320,640), pad

template<int PASS>
__global__ __launch_bounds__(512, 4) void edge_mfma(
    const float* __restrict__ atom, const float* __restrict__ nbr,
    const int* __restrict__ sidx, const int* __restrict__ nidx,
    const short* __restrict__ Wth, const short* __restrict__ Wtl,
    const float* __restrict__ bfp, const float* __restrict__ bcp,
    const float* __restrict__ scale, const float* __restrict__ shift,
    float* __restrict__ statsum, float* __restrict__ statsq,
    float* __restrict__ meanacc)
{
  __shared__ char xb[32*ROWB];   // 21 KB
  int t = threadIdx.x;
  int lane = t & 63, wid = t >> 6;
  int eh = wid >> 2, cq = wid & 3;        // 2 edge-halves x 4 col-quarters
  int r16 = lane & 15, g = lane >> 4;
  int colf = cq*16 + r16, colc = colf + 64;

  // B-fragments in registers (80 VGPR): lane holds W[k=ks*32+g*8 .. +7][col]
  short8v Bhf[5], Blf[5], Bhc[5], Blc[5];
  {
    const short* wfh = Wth + colf*160;
    const short* wch = Wth + colc*160;
    const short* wfl = Wtl + colf*160;
    const short* wcl = Wtl + colc*160;
    #pragma unroll
    for (int ks = 0; ks < 5; ks++){
      int o = ks*32 + g*8;
      Bhf[ks] = *(const short8v*)(wfh + o);
      Bhc[ks] = *(const short8v*)(wch + o);
      Blf[ks] = *(const short8v*)(wfl + o);
      Blc[ks] = *(const short8v*)(wcl + o);
    }
  }
  float bf = bfp[colf], bc = bcp[colf];
  float sf = 0.f, hf = 0.f, sc = 0.f, hc = 0.f;
  if (PASS == 1){ sf = scale[colf]; hf = shift[colf]; sc = scale[colc]; hc = shift[colc]; }
  float s0 = 0.f, q0 = 0.f, s1 = 0.f, q1 = 0.f;

  const char* arow = xb + (eh*16 + r16)*ROWB + g*16;

  for (int tile = blockIdx.x; tile < MEDGE/32; tile += gridDim.x){
    int e0 = tile*32;
    __syncthreads();
    // stage 32 edges: gather fp32, split hi/lo -> LDS
    for (int j = t; j < 640; j += 512){
      int e = j / 20, c = j - e*20;
      const float* src;
      if (c < 8)       src = atom + (size_t)sidx[e0+e]*64 + c*8;
      else if (c < 16) src = atom + (size_t)nidx[e0+e]*64 + (c-8)*8;
      else             src = nbr  + (size_t)(e0+e)*32 + (c-16)*8;
      float4 v0 = ld4(src), v1 = ld4(src+4);
      float fv[8] = {v0.x,v0.y,v0.z,v0.w,v1.x,v1.y,v1.z,v1.w};
      unsigned hw[4], lw[4];
      #pragma unroll
      for (int i = 0; i < 4; i++){
        unsigned ua = __float_as_uint(fv[2*i]), ub = __float_as_uint(fv[2*i+1]);
        unsigned ha = ua & 0xFFFF0000u, hb = ub & 0xFFFF0000u;
        hw[i] = (ha >> 16) | hb;
        lw[i] = (unsigned)rne_bf16(fv[2*i]   - __uint_as_float(ha))
              | ((unsigned)rne_bf16(fv[2*i+1] - __uint_as_float(hb)) << 16);
      }
      char* dst = xb + e*ROWB + c*16;
      *(uint4*)dst         = make_uint4(hw[0],hw[1],hw[2],hw[3]);
      *(uint4*)(dst + 320) = make_uint4(lw[0],lw[1],lw[2],lw[3]);
    }
    __syncthreads();

    f32x4 accf = {bf,bf,bf,bf}, accc = {bc,bc,bc,bc};
    #pragma unroll
    for (int ks = 0; ks < 5; ks++){
      short8v ah = *(const short8v*)(arow + ks*64);
      short8v al = *(const short8v*)(arow + 320 + ks*64);
      accf = __builtin_amdgcn_mfma_f32_16x16x32_bf16(ah, Bhf[ks], accf, 0, 0, 0);
      accc = __builtin_amdgcn_mfma_f32_16x16x32_bf16(ah, Bhc[ks], accc, 0, 0, 0);
      accf = __builtin_amdgcn_mfma_f32_16x16x32_bf16(al, Bhf[ks], accf, 0, 0, 0);
      accc = __builtin_amdgcn_mfma_f32_16x16x32_bf16(al, Bhc[ks], accc, 0, 0, 0);
      accf = __builtin_amdgcn_mfma_f32_16x16x32_bf16(ah, Blf[ks], accf, 0, 0, 0);
      accc = __builtin_amdgcn_mfma_f32_16x16x32_bf16(ah, Blc[ks], accc, 0, 0, 0);
    }

    if (PASS == 0){
      #pragma unroll
      for (int r = 0; r < 4; r++){
        float yf = accf[r], yc = accc[r];
        s0 += yf; q0 += yf*yf; s1 += yc; q1 += yc*yc;
      }
    } else {
      int ebase = e0 + eh*16 + g*4;   // C row = (lane>>4)*4 + reg
      #pragma unroll
      for (int r = 0; r < 4; r++){
        float f  = sigmoidf_(accf[r]*sf + hf);
        float c2 = softplusf_(accc[r]*sc + hc);
        int a = sidx[ebase + r];
        atomicAdd(&meanacc[(size_t)a*64 + colf], f*c2);
      }
    }
  }

  if (PASS == 0){
    s0 += __shfl_xor(s0,16); s0 += __shfl_xor(s0,32);
    q0 += __shfl_xor(q0,16); q0 += __shfl_xor(q0,32);
    s1 += __shfl_xor(s1,16); s1 += __shfl_xor(s1,32);
    q1 += __shfl_xor(q1,16); q1 += __shfl_xor(q1,32);
    if (g == 0){
      atomicAdd(&statsum[colf], s0); atomicAdd(&statsq[colf], q0);
      atomicAdd(&statsum[colc], s1); atomicAdd(&statsq[colc], q1);
    }
  }
}

// ---------------------------------------------------------------- BN finalize: scale/shift from stats
__global__ void bnfin_kernel(int nf, float invcnt,
                             const float* __restrict__ sum, const float* __restrict__ sq,
                             const float* __restrict__ g, const float* __restrict__ b,
                             float* __restrict__ scale, float* __restrict__ shift){
  int j = threadIdx.x;
  if (j < nf){
    float m = sum[j]*invcnt;
    float v = fmaxf(sq[j]*invcnt - m*m, 0.0f);
    float is = rsqrtf(v + 1e-5f);
    float s = g[j]*is;
    scale[j] = s;
    shift[j] = b[j] - m*s;
  }
}

// ---------------------------------------------------------------- mean = meanacc * recip, + stats over N
__global__ __launch_bounds__(256) void meanbn_stats(const float* __restrict__ recip,
                                                    float* __restrict__ meanacc,
                                                    float* __restrict__ sum, float* __restrict__ sq){
  int t = threadIdx.x;
  float s = 0.f, q = 0.f;
  for (size_t idx = (size_t)blockIdx.x*256 + t; idx < (size_t)NATOM*64; idx += (size_t)gridDim.x*256){
    int n = (int)(idx >> 6);
    float v = meanacc[idx]*recip[n];
    meanacc[idx] = v;
    s += v; q += v*v;
  }
  __shared__ float red[256][2];
  red[t][0]=s; red[t][1]=q;
  __syncthreads();
  if (t < 64){
    for (int i=1;i<4;i++){ s += red[t+64*i][0]; q += red[t+64*i][1]; }
    atomicAdd(&sum[t], s);
    atomicAdd(&sq[t], q);
  }
}

__global__ __launch_bounds__(256) void atom_update(float* __restrict__ atom,
                                                   const float* __restrict__ meanv,
                                                   const float* __restrict__ scale,
                                                   const float* __restrict__ shift){
  for (size_t idx = (size_t)blockIdx.x*256 + threadIdx.x; idx < (size_t)NATOM*64; idx += (size_t)gridDim.x*256){
    int j = (int)(idx & 63);
    atom[idx] = softplusf_(atom[idx] + meanv[idx]*scale[j] + shift[j]);
  }
}

// ---------------------------------------------------------------- gate MLP
__device__ __forceinline__ void gate_hidden(const float* __restrict__ atom, const float* Wl,
                                            const float* __restrict__ b1, int n, float* h){
  #pragma unroll
  for (int c=0;c<16;c++) h[c] = b1[c];
  #pragma unroll
  for (int k4=0;k4<16;k4++){
    float4 a = ld4(atom + (size_t)n*64 + k4*4);
    float av[4] = {a.x, a.y, a.z, a.w};
    #pragma unroll
    for (int q=0;q<4;q++){
      #pragma unroll
      for (int c=0;c<16;c++) h[c] += av[q]*Wl[(k4*4+q)*16 + c];
    }
  }
}

__global__ __launch_bounds__(256) void gate_stats(const float* __restrict__ atom,
                                                  const float* __restrict__ W1, const float* __restrict__ b1,
                                                  float* __restrict__ sum, float* __restrict__ sq){
  __shared__ float Wl[64*16];
  int t = threadIdx.x;
  *(float4*)&Wl[t*4] = ld4(W1 + t*4);
  __syncthreads();
  int n = blockIdx.x*256 + t;
  float h[16];
  gate_hidden(atom, Wl, b1, n, h);
  int lane = t & 63;
  #pragma unroll
  for (int c=0;c<16;c++){
    float v = h[c], v2 = h[c]*h[c];
    for (int off=32; off; off >>= 1){ v += __shfl_down(v, off); v2 += __shfl_down(v2, off); }
    if (lane == 0){ atomicAdd(&sum[c], v); atomicAdd(&sq[c], v2); }
  }
}

__global__ __launch_bounds__(256) void gate_apply(const float* __restrict__ atom,
                                                  const float* __restrict__ W1, const float* __restrict__ b1,
                                                  const float* __restrict__ scale, const float* __restrict__ shift,
                                                  const float* __restrict__ W2, const float* __restrict__ b2,
                                                  const int* __restrict__ cry,
                                                  float* __restrict__ gate, unsigned* __restrict__ gmaxk){
  __shared__ float Wl[64*16];
  int t = threadIdx.x;
  *(float4*)&Wl[t*4] = ld4(W1 + t*4);
  __syncthreads();
  int n = blockIdx.x*256 + t;
  float h[16];
  gate_hidden(atom, Wl, b1, n, h);
  float g = b2[0];
  #pragma unroll
  for (int c=0;c<16;c++){
    float y = fmaxf(h[c]*scale[c] + shift[c], 0.0f);
    g += y * W2[c];
  }
  gate[n] = g;
  atomicMax(&gmaxk[cry[n]], fkey(g));
}

__global__ __launch_bounds__(256) void gate_exp(float* __restrict__ gate,
                                                const float* __restrict__ aw,
                                                const int* __restrict__ cry,
                                                const unsigned* __restrict__ gmaxk,
                                                float* __restrict__ gsum){
  int n = blockIdx.x*256 + threadIdx.x;
  if (n < NATOM){
    int c = cry[n];
    float w = aw[n]*expf(gate[n] - fkeyinv(gmaxk[c]));
    gate[n] = w;
    atomicAdd(&gsum[c], w);
  }
}

__global__ __launch_bounds__(256) void crys_acc(const float* __restrict__ gate,
                                                const float* __restrict__ gsum,
                                                const int* __restrict__ cry,
                                                const float* __restrict__ atom,
                                                float* __restrict__ crys){
  for (size_t idx = (size_t)blockIdx.x*256 + threadIdx.x; idx < (size_t)NATOM*64; idx += (size_t)gridDim.x*256){
    int n = (int)(idx >> 6), j = (int)(idx & 63);
    int c = cry[n];
    float wn = gate[n] / (gsum[c] + 1e-13f);
    atomicAdd(&crys[(size_t)c*64 + j], wn*atom[idx]);
  }
}

// ---------------------------------------------------------------- fc head
__global__ __launch_bounds__(512) void fc_stats(const float* __restrict__ crys,
                                                const float* __restrict__ fcW, const float* __restrict__ fcb,
                                                float* __restrict__ hid,
                                                float* __restrict__ statsum, float* __restrict__ statsq){
  __shared__ float Wl[64*128];  // 32 KB
  __shared__ float cb[64][16];  // 4 KB
  int t = threadIdx.x;
  for (int j = t; j < 64*32; j += 512)
    *(float4*)&Wl[j*4] = ld4(fcW + j*4);
  int cg = t & 31, cr = t >> 5;
  float4 bias = ld4(fcb + cg*4);
  float ssum[4] = {0,0,0,0}, ssq[4] = {0,0,0,0};
  for (int chunk = blockIdx.x; chunk < NCRY/16; chunk += gridDim.x){
    int c0 = chunk*16;
    __syncthreads();
    for (int j = t; j < 256; j += 512){
      int rr = j & 15, c = j >> 4;
      float4 v = ld4(crys + (size_t)(c0+rr)*64 + c*4);
      int k = c*4;
      cb[k][rr]=v.x; cb[k+1][rr]=v.y; cb[k+2][rr]=v.z; cb[k+3][rr]=v.w;
    }
    __syncthreads();
    float4 acc = bias;
    #pragma unroll 4
    for (int k=0;k<64;k++){
      float a = cb[k][cr];
      float4 w = *(float4*)&Wl[k*128 + cg*4];
      acc.x += a*w.x; acc.y += a*w.y; acc.z += a*w.z; acc.w += a*w.w;
    }
    *(float4*)&hid[(size_t)(c0+cr)*128 + cg*4] = acc;
    ssum[0]+=acc.x; ssum[1]+=acc.y; ssum[2]+=acc.z; ssum[3]+=acc.w;
    ssq[0]+=acc.x*acc.x; ssq[1]+=acc.y*acc.y; ssq[2]+=acc.z*acc.z; ssq[3]+=acc.w*acc.w;
  }
  __syncthreads();
  float* red = Wl;
  #pragma unroll
  for (int q=0;q<4;q++){ red[t*8+q] = ssum[q]; red[t*8+4+q] = ssq[q]; }
  __syncthreads();
  if (t < 128){
    int cgj = t >> 2, q = t & 3;
    float s = 0.f, sq = 0.f;
    for (int cri=0; cri<16; cri++){
      int tt = cri*32 + cgj;
      s  += red[tt*8+q];
      sq += red[tt*8+4+q];
    }
    atomicAdd(&statsum[t], s);
    atomicAdd(&statsq[t], sq);
  }
}

__global__ __launch_bounds__(256) void out_kernel(const float* __restrict__ hid,
                                                  const float* __restrict__ scale, const float* __restrict__ shift,
                                                  const float* __restrict__ outW, const float* __restrict__ outb,
                                                  float* __restrict__ out){
  int c = blockIdx.x*4 + (threadIdx.x >> 6);
  int l = threadIdx.x & 63;
  float v = softplusf_(hid[(size_t)c*128 + l]*scale[l] + shift[l])*outW[l]
          + softplusf_(hid[(size_t)c*128 + 64 + l]*scale[64+l] + shift[64+l])*outW[64+l];
  for (int off=32; off; off >>= 1) v += __shfl_down(v, off);
  if (l == 0) out[c] = v + outb[0];
}

// ---------------------------------------------------------------- launch
extern "C" void kernel_launch(void* const* d_in, const int* in_sizes, int n_in,
                              void* d_out, int out_size, void* d_ws, size_t ws_size,
                              hipStream_t stream){
  const float* aw    = (const float*)d_in[0];
  const float* orig  = (const float*)d_in[1];
  const float* nbr   = (const float*)d_in[2];
  const int*   sidx  = (const int*)d_in[3];
  const int*   nidx  = (const int*)d_in[4];
  const int*   cry   = (const int*)d_in[5];
  const float* embW  = (const float*)d_in[6];
  const float* embB  = (const float*)d_in[7];
  const float* filtW = (const float*)d_in[8];
  const float* filtB = (const float*)d_in[9];
  const float* coreW = (const float*)d_in[10];
  const float* coreB = (const float*)d_in[11];
  const float* bnfg  = (const float*)d_in[12];
  const float* bnfb  = (const float*)d_in[13];
  const float* bncg  = (const float*)d_in[14];
  const float* bncb  = (const float*)d_in[15];
  const float* bnog  = (const float*)d_in[16];
  const float* bnob  = (const float*)d_in[17];
  const float* gW1   = (const float*)d_in[18];
  const float* gb1   = (const float*)d_in[19];
  const float* gbng  = (const float*)d_in[20];
  const float* gbnb  = (const float*)d_in[21];
  const float* gW2   = (const float*)d_in[22];
  const float* gb2   = (const float*)d_in[23];
  const float* fcW   = (const float*)d_in[24];
  const float* fcb   = (const float*)d_in[25];
  const float* fcbng = (const float*)d_in[26];
  const float* fcbnb = (const float*)d_in[27];
  const float* outW  = (const float*)d_in[28];
  const float* outb  = (const float*)d_in[29];
  float* out = (float*)d_out;

  float* ws      = (float*)d_ws;
  float* atom    = ws;                              // N*64
  float* meanacc = atom    + (size_t)NATOM*64;      // N*64
  float* cnt     = meanacc + (size_t)NATOM*64;      // N
  float* gate    = cnt     + NATOM;                 // N
  float* gmaxk   = gate    + NATOM;                 // C
  float* gsum    = gmaxk   + NCRY;                  // C
  float* crys    = gsum    + NCRY;                  // C*64
  float* hid     = crys    + (size_t)NCRY*64;       // C*128
  float* stats   = hid     + (size_t)NCRY*128;      // 256
  float* scale   = stats   + 256;                   // 128
  float* shift   = scale   + 128;                   // 128
  short* wth     = (short*)(shift + 128);           // 3*128*160 shorts
  short* wtl     = wth + 3*128*160;                 // 3*128*160 shorts
  (void)in_sizes; (void)n_in; (void)out_size; (void)ws_size;

  // prep: counts, W split/transpose, embedding
  hipMemsetAsync(cnt, 0, NATOM*sizeof(float), stream);
  cnt_kernel<<<2048, 256, 0, stream>>>(sidx, cnt);
  recip_kernel<<<NATOM/256, 256, 0, stream>>>(cnt);
  wprep<<<240, 256, 0, stream>>>(filtW, coreW, wth, wtl);
  embed_kernel<<<2048, 256, 0, stream>>>(orig, embW, embB, atom);

  // message-passing layers
  for (int i = 0; i < 3; ++i){
    const short* wthL = wth + (size_t)i*128*160;
    const short* wtlL = wtl + (size_t)i*128*160;
    const float* bf = filtB + i*64;
    const float* bc = coreB + i*64;
    hipMemsetAsync(stats, 0, 256*sizeof(float), stream);
    edge_mfma<0><<<2048, 512, 0, stream>>>(atom, nbr, sidx, nidx, wthL, wtlL, bf, bc,
                                           nullptr, nullptr, stats, stats+128, nullptr);
    bnfin_kernel<<<1, 64, 0, stream>>>(64, 1.0f/MEDGE, stats,    stats+128,    bnfg+i*64, bnfb+i*64, scale,    shift);
    bnfin_kernel<<<1, 64, 0, stream>>>(64, 1.0f/MEDGE, stats+64, stats+128+64, bncg+i*64, bncb+i*64, scale+64, shift+64);
    hipMemsetAsync(meanacc, 0, (size_t)NATOM*64*sizeof(float), stream);
    edge_mfma<1><<<2048, 512, 0, stream>>>(atom, nbr, sidx, nidx, wthL, wtlL, bf, bc,
                                           scale, shift, nullptr, nullptr, meanacc);
    hipMemsetAsync(stats, 0, 128*sizeof(float), stream);
    meanbn_stats<<<2048, 256, 0, stream>>>(cnt, meanacc, stats, stats+64);
    bnfin_kernel<<<1, 64, 0, stream>>>(64, 1.0f/NATOM, stats, stats+64, bnog+i*64, bnob+i*64, scale, shift);
    atom_update<<<2048, 256, 0, stream>>>(atom, meanacc, scale, shift);
  }

  // gate MLP + BN + attention pooling
  hipMemsetAsync(stats, 0, 32*sizeof(float), stream);
  gate_stats<<<NATOM/256, 256, 0, stream>>>(atom, gW1, gb1, stats, stats+16);
  bnfin_kernel<<<1, 16, 0, stream>>>(16, 1.0f/NATOM, stats, stats+16, gbng, gbnb, scale, shift);
  hipMemsetAsync(gmaxk, 0, NCRY*sizeof(unsigned), stream);
  gate_apply<<<NATOM/256, 256, 0, stream>>>(atom, gW1, gb1, scale, shift, gW2, gb2, cry, gate, (unsigned*)gmaxk);
  hipMemsetAsync(gsum, 0, NCRY*sizeof(float), stream);
  gate_exp<<<NATOM/256, 256, 0, stream>>>(gate, aw, cry, (const unsigned*)gmaxk, gsum);
  hipMemsetAsync(crys, 0, (size_t)NCRY*64*sizeof(float), stream);
  crys_acc<<<4096, 256, 0, stream>>>(gate, gsum, cry, atom, crys);

  // fc head
  hipMemsetAsync(stats, 0, 256*sizeof(float), stream);
  fc_stats<<<1024, 512, 0, stream>>>(crys, fcW, fcb, hid, stats, stats+128);
  bnfin_kernel<<<1, 128, 0, stream>>>(128, 1.0f/NCRY, stats, stats+128, fcbng, fcbnb, scale, shift);
  out_kernel<<<NCRY/4, 256, 0, stream>>>(hid, scale, shift, outW, outb, out);
}

// Round 3
// 3791.447 us; speedup vs baseline: 2.5064x; 1.0369x over previous
//
#include <hip/hip_runtime.h>
#include <cstdint>
#include <cstddef>

// Problem constants (from reference)
#define NATOM 262144
#define MEDGE 1048576
#define NCRY  32768
// ORIG=200, AF=64, NF=32, GH=16, H=128, NG=3

typedef __attribute__((ext_vector_type(8))) short short8v;   // 8 bf16 (4 VGPR)
typedef __attribute__((ext_vector_type(4))) float f32x4;     // MFMA acc

__device__ __forceinline__ float4 ld4(const float* p){ return *reinterpret_cast<const float4*>(p); }

__device__ __forceinline__ float softplusf_(float x){
  return fmaxf(x, 0.0f) + log1pf(expf(-fabsf(x)));
}
__device__ __forceinline__ float sigmoidf_(float x){ return 1.0f/(1.0f+expf(-x)); }

__device__ __forceinline__ unsigned short rne_bf16(float f){
  unsigned u = __float_as_uint(f);
  unsigned r = u + 0x7FFFu + ((u >> 16) & 1u);
  return (unsigned short)(r >> 16);
}

// monotonic float<->uint key for atomicMax-based segment max
__device__ __forceinline__ unsigned fkey(float x){
  unsigned b = __float_as_uint(x);
  return (b & 0x80000000u) ? ~b : (b | 0x80000000u);
}
__device__ __forceinline__ float fkeyinv(unsigned k){
  unsigned b = (k & 0x80000000u) ? (k & 0x7fffffffu) : ~k;
  return __uint_as_float(b);
}

// ---------------------------------------------------------------- counts
__global__ __launch_bounds__(256) void cnt_kernel(const int* __restrict__ sidx, float* __restrict__ cnt){
  for (int m = blockIdx.x*256 + threadIdx.x; m < MEDGE; m += gridDim.x*256)
    atomicAdd(&cnt[sidx[m]], 1.0f);
}
__global__ __launch_bounds__(256) void recip_kernel(float* __restrict__ cnt){
  int n = blockIdx.x*256 + threadIdx.x;
  if (n < NATOM) cnt[n] = 1.0f / fmaxf(cnt[n], 1.0f);
}

// ---------------------------------------------------------------- embedding: atom = orig @ embW + embB
__global__ __launch_bounds__(256) void embed_kernel(const float* __restrict__ orig,
                                                    const float* __restrict__ W,
                                                    const float* __restrict__ b,
                                                    float* __restrict__ atom){
  __shared__ float Wl[200*64];     // 51.2 KB
  __shared__ float rb[200][16];    // 12.8 KB, transposed row tile
  int t = threadIdx.x;
  for (int j = t; j < 200*16; j += 256){
    int k = j >> 4, c4 = j & 15;
    *(float4*)&Wl[k*64 + c4*4] = ld4(W + k*64 + c4*4);
  }
  int cg = t & 15, r = t >> 4;
  float4 bias = ld4(b + cg*4);
  for (int chunk = blockIdx.x; chunk < NATOM/16; chunk += gridDim.x){
    int n0 = chunk*16;
    __syncthreads();
    for (int j = t; j < 50*16; j += 256){
      int rr = j & 15, c = j >> 4;
      float4 v = ld4(orig + (size_t)(n0+rr)*200 + c*4);
      int k = c*4;
      rb[k][rr]=v.x; rb[k+1][rr]=v.y; rb[k+2][rr]=v.z; rb[k+3][rr]=v.w;
    }
    __syncthreads();
    float4 acc = bias;
    #pragma unroll 4
    for (int k = 0; k < 200; ++k){
      float a = rb[k][r];
      float4 w = *(float4*)&Wl[k*64 + cg*4];
      acc.x += a*w.x; acc.y += a*w.y; acc.z += a*w.z; acc.w += a*w.w;
    }
    *(float4*)&atom[(size_t)(n0+r)*64 + cg*4] = acc;
  }
}

// ---------------------------------------------------------------- W prep: fused+transposed+split-bf16
__global__ __launch_bounds__(256) void wprep(const float* __restrict__ filtW, const float* __restrict__ coreW,
                                             short* __restrict__ Wth, short* __restrict__ Wtl){
  int idx = blockIdx.x*256 + threadIdx.x;   // 3*128*160 = 61440
  if (idx >= 3*128*160) return;
  int k = idx % 160; int rest = idx / 160; int c = rest & 127; int layer = rest >> 7;
  float w = (c < 64) ? filtW[((size_t)layer*160 + k)*64 + c] : coreW[((size_t)layer*160 + k)*64 + (c-64)];
  unsigned u = __float_as_uint(w);
  unsigned h = u & 0xFFFF0000u;
  Wth[idx] = (short)(h >> 16);
  Wtl[idx] = (short)rne_bf16(w - __uint_as_float(h));
}

// ---------------------------------------------------------------- edge GEMM via split-bf16 MFMA
#define ROWB 656   // 328 bf16: hi[0..160) at bytes [0,320), lo at [320,640), pad

template<int PASS>
__global__ __launch_bounds__(512, 4) void edge_mfma(
    const float* __restrict__ atom, const float* __restrict__ nbr,
    const int* __restrict__ sidx, const int* __restrict__ nidx,
    const short* __restrict__ Wth, const short* __restrict__ Wtl,
    const float* __restrict__ bfp, const float* __restrict__ bcp,
    const float* __restrict__ scale, const float* __restrict__ shift,
    float* __restrict__ statsum, float* __restrict__ statsq,
    float* __restrict__ meanacc)
{
  __shared__ char xb[32*ROWB];   // 21 KB
  int t = threadIdx.x;
  int lane = t & 63, wid = t >> 6;
  int eh = wid >> 2, cq = wid & 3;        // 2 edge-halves x 4 col-quarters
  int r16 = lane & 15, g = lane >> 4;
  int colf = cq*16 + r16, colc = colf + 64;

  short8v Bhf[5], Blf[5], Bhc[5], Blc[5];
  {
    const short* wfh = Wth + colf*160;
    const short* wch = Wth + colc*160;
    const short* wfl = Wtl + colf*160;
    const short* wcl = Wtl + colc*160;
    #pragma unroll
    for (int ks = 0; ks < 5; ks++){
      int o = ks*32 + g*8;
      Bhf[ks] = *(const short8v*)(wfh + o);
      Bhc[ks] = *(const short8v*)(wch + o);
      Blf[ks] = *(const short8v*)(wfl + o);
      Blc[ks] = *(const short8v*)(wcl + o);
    }
  }
  float bf = bfp[colf], bc = bcp[colf];
  float sf = 0.f, hf = 0.f, sc = 0.f, hc = 0.f;
  if (PASS == 1){ sf = scale[colf]; hf = shift[colf]; sc = scale[colc]; hc = shift[colc]; }
  float s0 = 0.f, q0 = 0.f, s1 = 0.f, q1 = 0.f;

  const char* arow = xb + (eh*16 + r16)*ROWB + g*16;

  for (int tile = blockIdx.x; tile < MEDGE/32; tile += gridDim.x){
    int e0 = tile*32;
    __syncthreads();
    for (int j = t; j < 640; j += 512){
      int e = j / 20, c = j - e*20;
      const float* src;
      if (c < 8)       src = atom + (size_t)sidx[e0+e]*64 + c*8;
      else if (c < 16) src = atom + (size_t)nidx[e0+e]*64 + (c-8)*8;
      else             src = nbr  + (size_t)(e0+e)*32 + (c-16)*8;
      float4 v0 = ld4(src), v1 = ld4(src+4);
      float fv[8] = {v0.x,v0.y,v0.z,v0.w,v1.x,v1.y,v1.z,v1.w};
      unsigned hw[4], lw[4];
      #pragma unroll
      for (int i = 0; i < 4; i++){
        unsigned ua = __float_as_uint(fv[2*i]), ub = __float_as_uint(fv[2*i+1]);
        unsigned ha = ua & 0xFFFF0000u, hb = ub & 0xFFFF0000u;
        hw[i] = (ha >> 16) | hb;
        lw[i] = (unsigned)rne_bf16(fv[2*i]   - __uint_as_float(ha))
              | ((unsigned)rne_bf16(fv[2*i+1] - __uint_as_float(hb)) << 16);
      }
      char* dst = xb + e*ROWB + c*16;
      *(uint4*)dst         = make_uint4(hw[0],hw[1],hw[2],hw[3]);
      *(uint4*)(dst + 320) = make_uint4(lw[0],lw[1],lw[2],lw[3]);
    }
    __syncthreads();

    f32x4 accf = {bf,bf,bf,bf}, accc = {bc,bc,bc,bc};
    #pragma unroll
    for (int ks = 0; ks < 5; ks++){
      short8v ah = *(const short8v*)(arow + ks*64);
      short8v al = *(const short8v*)(arow + 320 + ks*64);
      accf = __builtin_amdgcn_mfma_f32_16x16x32_bf16(ah, Bhf[ks], accf, 0, 0, 0);
      accc = __builtin_amdgcn_mfma_f32_16x16x32_bf16(ah, Bhc[ks], accc, 0, 0, 0);
      accf = __builtin_amdgcn_mfma_f32_16x16x32_bf16(al, Bhf[ks], accf, 0, 0, 0);
      accc = __builtin_amdgcn_mfma_f32_16x16x32_bf16(al, Bhc[ks], accc, 0, 0, 0);
      accf = __builtin_amdgcn_mfma_f32_16x16x32_bf16(ah, Blf[ks], accf, 0, 0, 0);
      accc = __builtin_amdgcn_mfma_f32_16x16x32_bf16(ah, Blc[ks], accc, 0, 0, 0);
    }

    if (PASS == 0){
      #pragma unroll
      for (int r = 0; r < 4; r++){
        float yf = accf[r], yc = accc[r];
        s0 += yf; q0 += yf*yf; s1 += yc; q1 += yc*yc;
      }
    } else {
      int ebase = e0 + eh*16 + g*4;   // C row = (lane>>4)*4 + reg
      #pragma unroll
      for (int r = 0; r < 4; r++){
        float f  = sigmoidf_(accf[r]*sf + hf);
        float c2 = softplusf_(accc[r]*sc + hc);
        int a = sidx[ebase + r];
        atomicAdd(&meanacc[(size_t)a*64 + colf], f*c2);
      }
    }
  }

  if (PASS == 0){
    s0 += __shfl_xor(s0,16); s0 += __shfl_xor(s0,32);
    q0 += __shfl_xor(q0,16); q0 += __shfl_xor(q0,32);
    s1 += __shfl_xor(s1,16); s1 += __shfl_xor(s1,32);
    q1 += __shfl_xor(q1,16); q1 += __shfl_xor(q1,32);
    if (g == 0){
      atomicAdd(&statsum[colf], s0); atomicAdd(&statsq[colf], q0);
      atomicAdd(&statsum[colc], s1); atomicAdd(&statsq[colc], q1);
    }
  }
}

// ---------------------------------------------------------------- BN finalize: scale/shift from stats
__global__ void bnfin_kernel(int nf, float invcnt,
                             const float* __restrict__ sum, const float* __restrict__ sq,
                             const float* __restrict__ g, const float* __restrict__ b,
                             float* __restrict__ scale, float* __restrict__ shift){
  int j = threadIdx.x;
  if (j < nf){
    float m = sum[j]*invcnt;
    float v = fmaxf(sq[j]*invcnt - m*m, 0.0f);
    float is = rsqrtf(v + 1e-5f);
    float s = g[j]*is;
    scale[j] = s;
    shift[j] = b[j] - m*s;
  }
}

// ---------------------------------------------------------------- mean = meanacc * recip, + stats over N
__global__ __launch_bounds__(256) void meanbn_stats(const float* __restrict__ recip,
                                                    float* __restrict__ meanacc,
                                                    float* __restrict__ sum, float* __restrict__ sq){
  int t = threadIdx.x;
  float s = 0.f, q = 0.f;
  for (size_t idx = (size_t)blockIdx.x*256 + t; idx < (size_t)NATOM*64; idx += (size_t)gridDim.x*256){
    int n = (int)(idx >> 6);
    float v = meanacc[idx]*recip[n];
    meanacc[idx] = v;
    s += v; q += v*v;
  }
  __shared__ float red[256][2];
  red[t][0]=s; red[t][1]=q;
  __syncthreads();
  if (t < 64){
    for (int i=1;i<4;i++){ s += red[t+64*i][0]; q += red[t+64*i][1]; }
    atomicAdd(&sum[t], s);
    atomicAdd(&sq[t], q);
  }
}

__global__ __launch_bounds__(256) void atom_update(float* __restrict__ atom,
                                                   const float* __restrict__ meanv,
                                                   const float* __restrict__ scale,
                                                   const float* __restrict__ shift){
  for (size_t idx = (size_t)blockIdx.x*256 + threadIdx.x; idx < (size_t)NATOM*64; idx += (size_t)gridDim.x*256){
    int j = (int)(idx & 63);
    atom[idx] = softplusf_(atom[idx] + meanv[idx]*scale[j] + shift[j]);
  }
}

// ---------------------------------------------------------------- gate MLP, pass 1: h = atom @ W1 + b1, stats
// coalesced LDS-staged; h written to hbuf (reuses meanacc ws)
__global__ __launch_bounds__(256, 2) void gate_pass1(const float* __restrict__ atom,
                                                     const float* __restrict__ W1, const float* __restrict__ b1,
                                                     float* __restrict__ hbuf,
                                                     float* __restrict__ sum, float* __restrict__ sq){
  __shared__ float As[256*65];   // 66.6 KB, +1 pad -> conflict-free
  __shared__ float Wl[64*16];    // 4 KB
  int t = threadIdx.x;
  *(float4*)&Wl[t*4] = ld4(W1 + t*4);
  const float* src = atom + (size_t)blockIdx.x*256*64;
  #pragma unroll
  for (int j = 0; j < 16; j++){
    int idx = j*256 + t;               // float4 index, fully coalesced
    float4 v = ld4(src + idx*4);
    int r = idx >> 4, c = (idx & 15)*4;
    float* d = &As[r*65 + c];
    d[0]=v.x; d[1]=v.y; d[2]=v.z; d[3]=v.w;
  }
  __syncthreads();
  float h[16];
  #pragma unroll
  for (int c=0;c<16;c++) h[c] = b1[c];
  const float* ar = &As[t*65];
  #pragma unroll 8
  for (int k=0;k<64;k++){
    float a = ar[k];
    #pragma unroll
    for (int c=0;c<16;c++) h[c] += a*Wl[k*16+c];
  }
  size_t n = (size_t)blockIdx.x*256 + t;
  #pragma unroll
  for (int c=0;c<16;c+=4)
    *(float4*)&hbuf[n*16+c] = make_float4(h[c],h[c+1],h[c+2],h[c+3]);
  #pragma unroll
  for (int c=0;c<16;c++){
    float v = h[c], v2 = h[c]*h[c];
    for (int off=32; off; off>>=1){ v += __shfl_down(v,off); v2 += __shfl_down(v2,off); }
    if ((t&63)==0){ atomicAdd(&sum[c], v); atomicAdd(&sq[c], v2); }
  }
}

// ---------------------------------------------------------------- gate MLP, pass 2: BN+relu+W2, segment max
__global__ __launch_bounds__(256) void gate_pass2(const float* __restrict__ hbuf,
                                                  const float* __restrict__ scale, const float* __restrict__ shift,
                                                  const float* __restrict__ W2, const float* __restrict__ b2,
                                                  const int* __restrict__ cry,
                                                  float* __restrict__ gate, unsigned* __restrict__ gmaxk){
  int n = blockIdx.x*256 + threadIdx.x;
  float g = b2[0];
  #pragma unroll
  for (int c=0;c<16;c+=4){
    float4 hv = ld4(hbuf + (size_t)n*16 + c);
    float4 sc = ld4(scale + c), sh = ld4(shift + c), w = ld4(W2 + c);
    g += fmaxf(hv.x*sc.x+sh.x,0.f)*w.x + fmaxf(hv.y*sc.y+sh.y,0.f)*w.y
       + fmaxf(hv.z*sc.z+sh.z,0.f)*w.z + fmaxf(hv.w*sc.w+sh.w,0.f)*w.w;
  }
  gate[n] = g;
  atomicMax(&gmaxk[cry[n]], fkey(g));
}

__global__ __launch_bounds__(256) void gate_exp(float* __restrict__ gate,
                                                const float* __restrict__ aw,
                                                const int* __restrict__ cry,
                                                const unsigned* __restrict__ gmaxk,
                                                float* __restrict__ gsum){
  int n = blockIdx.x*256 + threadIdx.x;
  if (n < NATOM){
    int c = cry[n];
    float w = aw[n]*expf(gate[n] - fkeyinv(gmaxk[c]));
    gate[n] = w;
    atomicAdd(&gsum[c], w);
  }
}

__global__ __launch_bounds__(256) void crys_acc(const float* __restrict__ gate,
                                                const float* __restrict__ gsum,
                                                const int* __restrict__ cry,
                                                const float* __restrict__ atom,
                                                float* __restrict__ crys){
  for (size_t idx = (size_t)blockIdx.x*256 + threadIdx.x; idx < (size_t)NATOM*64; idx += (size_t)gridDim.x*256){
    int n = (int)(idx >> 6), j = (int)(idx & 63);
    int c = cry[n];
    float wn = gate[n] / (gsum[c] + 1e-13f);
    atomicAdd(&crys[(size_t)c*64 + j], wn*atom[idx]);
  }
}

// ---------------------------------------------------------------- fc head
__global__ __launch_bounds__(512) void fc_stats(const float* __restrict__ crys,
                                                const float* __restrict__ fcW, const float* __restrict__ fcb,
                                                float* __restrict__ hid,
                                                float* __restrict__ statsum, float* __restrict__ statsq){
  __shared__ float Wl[64*128];  // 32 KB
  __shared__ float cb[64][16];  // 4 KB
  int t = threadIdx.x;
  for (int j = t; j < 64*32; j += 512)
    *(float4*)&Wl[j*4] = ld4(fcW + j*4);
  int cg = t & 31, cr = t >> 5;
  float4 bias = ld4(fcb + cg*4);
  float ssum[4] = {0,0,0,0}, ssq[4] = {0,0,0,0};
  for (int chunk = blockIdx.x; chunk < NCRY/16; chunk += gridDim.x){
    int c0 = chunk*16;
    __syncthreads();
    for (int j = t; j < 256; j += 512){
      int rr = j & 15, c = j >> 4;
      float4 v = ld4(crys + (size_t)(c0+rr)*64 + c*4);
      int k = c*4;
      cb[k][rr]=v.x; cb[k+1][rr]=v.y; cb[k+2][rr]=v.z; cb[k+3][rr]=v.w;
    }
    __syncthreads();
    float4 acc = bias;
    #pragma unroll 4
    for (int k=0;k<64;k++){
      float a = cb[k][cr];
      float4 w = *(float4*)&Wl[k*128 + cg*4];
      acc.x += a*w.x; acc.y += a*w.y; acc.z += a*w.z; acc.w += a*w.w;
    }
    *(float4*)&hid[(size_t)(c0+cr)*128 + cg*4] = acc;
    ssum[0]+=acc.x; ssum[1]+=acc.y; ssum[2]+=acc.z; ssum[3]+=acc.w;
    ssq[0]+=acc.x*acc.x; ssq[1]+=acc.y*acc.y; ssq[2]+=acc.z*acc.z; ssq[3]+=acc.w*acc.w;
  }
  __syncthreads();
  float* red = Wl;
  #pragma unroll
  for (int q=0;q<4;q++){ red[t*8+q] = ssum[q]; red[t*8+4+q] = ssq[q]; }
  __syncthreads();
  if (t < 128){
    int cgj = t >> 2, q = t & 3;
    float s = 0.f, sq = 0.f;
    for (int cri=0; cri<16; cri++){
      int tt = cri*32 + cgj;
      s  += red[tt*8+q];
      sq += red[tt*8+4+q];
    }
    atomicAdd(&statsum[t], s);
    atomicAdd(&statsq[t], sq);
  }
}

__global__ __launch_bounds__(256) void out_kernel(const float* __restrict__ hid,
                                                  const float* __restrict__ scale, const float* __restrict__ shift,
                                                  const float* __restrict__ outW, const float* __restrict__ outb,
                                                  float* __restrict__ out){
  int c = blockIdx.x*4 + (threadIdx.x >> 6);
  int l = threadIdx.x & 63;
  float v = softplusf_(hid[(size_t)c*128 + l]*scale[l] + shift[l])*outW[l]
          + softplusf_(hid[(size_t)c*128 + 64 + l]*scale[64+l] + shift[64+l])*outW[64+l];
  for (int off=32; off; off >>= 1) v += __shfl_down(v, off);
  if (l == 0) out[c] = v + outb[0];
}

// ---------------------------------------------------------------- launch
extern "C" void kernel_launch(void* const* d_in, const int* in_sizes, int n_in,
                              void* d_out, int out_size, void* d_ws, size_t ws_size,
                              hipStream_t stream){
  const float* aw    = (const float*)d_in[0];
  const float* orig  = (const float*)d_in[1];
  const float* nbr   = (const float*)d_in[2];
  const int*   sidx  = (const int*)d_in[3];
  const int*   nidx  = (const int*)d_in[4];
  const int*   cry   = (const int*)d_in[5];
  const float* embW  = (const float*)d_in[6];
  const float* embB  = (const float*)d_in[7];
  const float* filtW = (const float*)d_in[8];
  const float* filtB = (const float*)d_in[9];
  const float* coreW = (const float*)d_in[10];
  const float* coreB = (const float*)d_in[11];
  const float* bnfg  = (const float*)d_in[12];
  const float* bnfb  = (const float*)d_in[13];
  const float* bncg  = (const float*)d_in[14];
  const float* bncb  = (const float*)d_in[15];
  const float* bnog  = (const float*)d_in[16];
  const float* bnob  = (const float*)d_in[17];
  const float* gW1   = (const float*)d_in[18];
  const float* gb1   = (const float*)d_in[19];
  const float* gbng  = (const float*)d_in[20];
  const float* gbnb  = (const float*)d_in[21];
  const float* gW2   = (const float*)d_in[22];
  const float* gb2   = (const float*)d_in[23];
  const float* fcW   = (const float*)d_in[24];
  const float* fcb   = (const float*)d_in[25];
  const float* fcbng = (const float*)d_in[26];
  const float* fcbnb = (const float*)d_in[27];
  const float* outW  = (const float*)d_in[28];
  const float* outb  = (const float*)d_in[29];
  float* out = (float*)d_out;

  float* ws      = (float*)d_ws;
  float* atom    = ws;                              // N*64
  float* meanacc = atom    + (size_t)NATOM*64;      // N*64  (reused as hbuf after MP)
  float* cnt     = meanacc + (size_t)NATOM*64;      // N
  float* gate    = cnt     + NATOM;                 // N
  float* gmaxk   = gate    + NATOM;                 // C
  float* gsum    = gmaxk   + NCRY;                  // C
  float* crys    = gsum    + NCRY;                  // C*64
  float* hid     = crys    + (size_t)NCRY*64;       // C*128
  float* stats   = hid     + (size_t)NCRY*128;      // 256
  float* scale   = stats   + 256;                   // 128
  float* shift   = scale   + 128;                   // 128
  short* wth     = (short*)(shift + 128);           // 3*128*160 shorts
  short* wtl     = wth + 3*128*160;                 // 3*128*160 shorts
  (void)in_sizes; (void)n_in; (void)out_size; (void)ws_size;

  // prep: counts, W split/transpose, embedding
  hipMemsetAsync(cnt, 0, NATOM*sizeof(float), stream);
  cnt_kernel<<<2048, 256, 0, stream>>>(sidx, cnt);
  recip_kernel<<<NATOM/256, 256, 0, stream>>>(cnt);
  wprep<<<240, 256, 0, stream>>>(filtW, coreW, wth, wtl);
  embed_kernel<<<2048, 256, 0, stream>>>(orig, embW, embB, atom);

  // message-passing layers
  for (int i = 0; i < 3; ++i){
    const short* wthL = wth + (size_t)i*128*160;
    const short* wtlL = wtl + (size_t)i*128*160;
    const float* bf = filtB + i*64;
    const float* bc = coreB + i*64;
    hipMemsetAsync(stats, 0, 256*sizeof(float), stream);
    edge_mfma<0><<<2048, 512, 0, stream>>>(atom, nbr, sidx, nidx, wthL, wtlL, bf, bc,
                                           nullptr, nullptr, stats, stats+128, nullptr);
    bnfin_kernel<<<1, 64, 0, stream>>>(64, 1.0f/MEDGE, stats,    stats+128,    bnfg+i*64, bnfb+i*64, scale,    shift);
    bnfin_kernel<<<1, 64, 0, stream>>>(64, 1.0f/MEDGE, stats+64, stats+128+64, bncg+i*64, bncb+i*64, scale+64, shift+64);
    hipMemsetAsync(meanacc, 0, (size_t)NATOM*64*sizeof(float), stream);
    edge_mfma<1><<<2048, 512, 0, stream>>>(atom, nbr, sidx, nidx, wthL, wtlL, bf, bc,
                                           scale, shift, nullptr, nullptr, meanacc);
    hipMemsetAsync(stats, 0, 128*sizeof(float), stream);
    meanbn_stats<<<2048, 256, 0, stream>>>(cnt, meanacc, stats, stats+64);
    bnfin_kernel<<<1, 64, 0, stream>>>(64, 1.0f/NATOM, stats, stats+64, bnog+i*64, bnob+i*64, scale, shift);
    atom_update<<<2048, 256, 0, stream>>>(atom, meanacc, scale, shift);
  }

  // gate MLP + BN + attention pooling   (hbuf reuses meanacc)
  float* hbuf = meanacc;
  hipMemsetAsync(stats, 0, 32*sizeof(float), stream);
  gate_pass1<<<NATOM/256, 256, 0, stream>>>(atom, gW1, gb1, hbuf, stats, stats+16);
  bnfin_kernel<<<1, 16, 0, stream>>>(16, 1.0f/NATOM, stats, stats+16, gbng, gbnb, scale, shift);
  hipMemsetAsync(gmaxk, 0, NCRY*sizeof(unsigned), stream);
  gate_pass2<<<NATOM/256, 256, 0, stream>>>(hbuf, scale, shift, gW2, gb2, cry, gate, (unsigned*)gmaxk);
  hipMemsetAsync(gsum, 0, NCRY*sizeof(float), stream);
  gate_exp<<<NATOM/256, 256, 0, stream>>>(gate, aw, cry, (const unsigned*)gmaxk, gsum);
  hipMemsetAsync(crys, 0, (size_t)NCRY*64*sizeof(float), stream);
  crys_acc<<<4096, 256, 0, stream>>>(gate, gsum, cry, atom, crys);

  // fc head
  hipMemsetAsync(stats, 0, 256*sizeof(float), stream);
  fc_stats<<<1024, 512, 0, stream>>>(crys, fcW, fcb, hid, stats, stats+128);
  bnfin_kernel<<<1, 128, 0, stream>>>(128, 1.0f/NCRY, stats, stats+128, fcbng, fcbnb, scale, shift);
  out_kernel<<<NCRY/4, 256, 0, stream>>>(hid, scale, shift, outW, outb, out);
}

// Round 4
// 3601.998 us; speedup vs baseline: 2.6382x; 1.0526x over previous
//
#include <hip/hip_runtime.h>
#include <cstdint>
#include <cstddef>

// Problem constants (from reference)
#define NATOM 262144
#define MEDGE 1048576
#define NCRY  32768
// ORIG=200, AF=64, NF=32, GH=16, H=128, NG=3

typedef __attribute__((ext_vector_type(8))) short short8v;   // 8 bf16 (4 VGPR)
typedef __attribute__((ext_vector_type(4))) float f32x4;     // MFMA acc

__device__ __forceinline__ float4 ld4(const float* p){ return *reinterpret_cast<const float4*>(p); }

__device__ __forceinline__ float softplusf_(float x){
  return fmaxf(x, 0.0f) + log1pf(expf(-fabsf(x)));
}
__device__ __forceinline__ float sigmoidf_(float x){ return 1.0f/(1.0f+expf(-x)); }

__device__ __forceinline__ unsigned short rne_bf16(float f){
  unsigned u = __float_as_uint(f);
  unsigned r = u + 0x7FFFu + ((u >> 16) & 1u);
  return (unsigned short)(r >> 16);
}

// monotonic float<->uint key for atomicMax-based segment max
__device__ __forceinline__ unsigned fkey(float x){
  unsigned b = __float_as_uint(x);
  return (b & 0x80000000u) ? ~b : (b | 0x80000000u);
}
__device__ __forceinline__ float fkeyinv(unsigned k){
  unsigned b = (k & 0x80000000u) ? (k & 0x7fffffffu) : ~k;
  return __uint_as_float(b);
}

// ---------------------------------------------------------------- generic column reduce: out[c] = sum_b part[b*nc+c]
__global__ __launch_bounds__(256) void colreduce(const float* __restrict__ part, float* __restrict__ out,
                                                 int nb, int nc){
  __shared__ float red[4][64];
  int c64 = threadIdx.x & 63, sl = threadIdx.x >> 6;
  int c = blockIdx.x*64 + c64;
  float s = 0.f;
  if (c < nc)
    for (int b = sl; b < nb; b += 4) s += part[(size_t)b*nc + c];
  red[sl][c64] = s;
  __syncthreads();
  if (sl == 0 && c < nc)
    out[c] = red[0][c64] + red[1][c64] + red[2][c64] + red[3][c64];
}

// ---------------------------------------------------------------- counts
__global__ __launch_bounds__(256) void cnt_kernel(const int* __restrict__ sidx, float* __restrict__ cnt){
  for (int m = blockIdx.x*256 + threadIdx.x; m < MEDGE; m += gridDim.x*256)
    atomicAdd(&cnt[sidx[m]], 1.0f);
}
__global__ __launch_bounds__(256) void recip_kernel(float* __restrict__ cnt){
  int n = blockIdx.x*256 + threadIdx.x;
  if (n < NATOM) cnt[n] = 1.0f / fmaxf(cnt[n], 1.0f);
}

// ---------------------------------------------------------------- embedding: atom = orig @ embW + embB
__global__ __launch_bounds__(256) void embed_kernel(const float* __restrict__ orig,
                                                    const float* __restrict__ W,
                                                    const float* __restrict__ b,
                                                    float* __restrict__ atom){
  __shared__ float Wl[200*64];     // 51.2 KB
  __shared__ float rb[200][16];    // 12.8 KB, transposed row tile
  int t = threadIdx.x;
  for (int j = t; j < 200*16; j += 256){
    int k = j >> 4, c4 = j & 15;
    *(float4*)&Wl[k*64 + c4*4] = ld4(W + k*64 + c4*4);
  }
  int cg = t & 15, r = t >> 4;
  float4 bias = ld4(b + cg*4);
  for (int chunk = blockIdx.x; chunk < NATOM/16; chunk += gridDim.x){
    int n0 = chunk*16;
    __syncthreads();
    for (int j = t; j < 50*16; j += 256){
      int rr = j & 15, c = j >> 4;
      float4 v = ld4(orig + (size_t)(n0+rr)*200 + c*4);
      int k = c*4;
      rb[k][rr]=v.x; rb[k+1][rr]=v.y; rb[k+2][rr]=v.z; rb[k+3][rr]=v.w;
    }
    __syncthreads();
    float4 acc = bias;
    #pragma unroll 4
    for (int k = 0; k < 200; ++k){
      float a = rb[k][r];
      float4 w = *(float4*)&Wl[k*64 + cg*4];
      acc.x += a*w.x; acc.y += a*w.y; acc.z += a*w.z; acc.w += a*w.w;
    }
    *(float4*)&atom[(size_t)(n0+r)*64 + cg*4] = acc;
  }
}

// ---------------------------------------------------------------- W prep: fused+transposed+split-bf16
__global__ __launch_bounds__(256) void wprep(const float* __restrict__ filtW, const float* __restrict__ coreW,
                                             short* __restrict__ Wth, short* __restrict__ Wtl){
  int idx = blockIdx.x*256 + threadIdx.x;   // 3*128*160 = 61440
  if (idx >= 3*128*160) return;
  int k = idx % 160; int rest = idx / 160; int c = rest & 127; int layer = rest >> 7;
  float w = (c < 64) ? filtW[((size_t)layer*160 + k)*64 + c] : coreW[((size_t)layer*160 + k)*64 + (c-64)];
  unsigned u = __float_as_uint(w);
  unsigned h = u & 0xFFFF0000u;
  Wth[idx] = (short)(h >> 16);
  Wtl[idx] = (short)rne_bf16(w - __uint_as_float(h));
}

// ---------------------------------------------------------------- edge GEMM via split-bf16 MFMA
#define ROWB 656   // 328 bf16: hi[0..160) at bytes [0,320), lo at [320,640), pad

template<int PASS>
__global__ __launch_bounds__(512, 4) void edge_mfma(
    const float* __restrict__ atom, const float* __restrict__ nbr,
    const int* __restrict__ sidx, const int* __restrict__ nidx,
    const short* __restrict__ Wth, const short* __restrict__ Wtl,
    const float* __restrict__ bfp, const float* __restrict__ bcp,
    const float* __restrict__ scale, const float* __restrict__ shift,
    float* __restrict__ partial,
    float* __restrict__ meanacc)
{
  __shared__ char xb[32*ROWB];   // 21 KB
  int t = threadIdx.x;
  int lane = t & 63, wid = t >> 6;
  int eh = wid >> 2, cq = wid & 3;        // 2 edge-halves x 4 col-quarters
  int r16 = lane & 15, g = lane >> 4;
  int colf = cq*16 + r16, colc = colf + 64;

  short8v Bhf[5], Blf[5], Bhc[5], Blc[5];
  {
    const short* wfh = Wth + colf*160;
    const short* wch = Wth + colc*160;
    const short* wfl = Wtl + colf*160;
    const short* wcl = Wtl + colc*160;
    #pragma unroll
    for (int ks = 0; ks < 5; ks++){
      int o = ks*32 + g*8;
      Bhf[ks] = *(const short8v*)(wfh + o);
      Bhc[ks] = *(const short8v*)(wch + o);
      Blf[ks] = *(const short8v*)(wfl + o);
      Blc[ks] = *(const short8v*)(wcl + o);
    }
  }
  float bf = bfp[colf], bc = bcp[colf];
  float sf = 0.f, hf = 0.f, sc = 0.f, hc = 0.f;
  if (PASS == 1){ sf = scale[colf]; hf = shift[colf]; sc = scale[colc]; hc = shift[colc]; }
  float s0 = 0.f, q0 = 0.f, s1 = 0.f, q1 = 0.f;

  const char* arow = xb + (eh*16 + r16)*ROWB + g*16;

  for (int tile = blockIdx.x; tile < MEDGE/32; tile += gridDim.x){
    int e0 = tile*32;
    __syncthreads();
    for (int j = t; j < 640; j += 512){
      int e = j / 20, c = j - e*20;
      const float* src;
      if (c < 8)       src = atom + (size_t)sidx[e0+e]*64 + c*8;
      else if (c < 16) src = atom + (size_t)nidx[e0+e]*64 + (c-8)*8;
      else             src = nbr  + (size_t)(e0+e)*32 + (c-16)*8;
      float4 v0 = ld4(src), v1 = ld4(src+4);
      float fv[8] = {v0.x,v0.y,v0.z,v0.w,v1.x,v1.y,v1.z,v1.w};
      unsigned hw[4], lw[4];
      #pragma unroll
      for (int i = 0; i < 4; i++){
        unsigned ua = __float_as_uint(fv[2*i]), ub = __float_as_uint(fv[2*i+1]);
        unsigned ha = ua & 0xFFFF0000u, hb = ub & 0xFFFF0000u;
        hw[i] = (ha >> 16) | hb;
        lw[i] = (unsigned)rne_bf16(fv[2*i]   - __uint_as_float(ha))
              | ((unsigned)rne_bf16(fv[2*i+1] - __uint_as_float(hb)) << 16);
      }
      char* dst = xb + e*ROWB + c*16;
      *(uint4*)dst         = make_uint4(hw[0],hw[1],hw[2],hw[3]);
      *(uint4*)(dst + 320) = make_uint4(lw[0],lw[1],lw[2],lw[3]);
    }
    __syncthreads();

    f32x4 accf = {bf,bf,bf,bf}, accc = {bc,bc,bc,bc};
    #pragma unroll
    for (int ks = 0; ks < 5; ks++){
      short8v ah = *(const short8v*)(arow + ks*64);
      short8v al = *(const short8v*)(arow + 320 + ks*64);
      accf = __builtin_amdgcn_mfma_f32_16x16x32_bf16(ah, Bhf[ks], accf, 0, 0, 0);
      accc = __builtin_amdgcn_mfma_f32_16x16x32_bf16(ah, Bhc[ks], accc, 0, 0, 0);
      accf = __builtin_amdgcn_mfma_f32_16x16x32_bf16(al, Bhf[ks], accf, 0, 0, 0);
      accc = __builtin_amdgcn_mfma_f32_16x16x32_bf16(al, Bhc[ks], accc, 0, 0, 0);
      accf = __builtin_amdgcn_mfma_f32_16x16x32_bf16(ah, Blf[ks], accf, 0, 0, 0);
      accc = __builtin_amdgcn_mfma_f32_16x16x32_bf16(ah, Blc[ks], accc, 0, 0, 0);
    }

    if (PASS == 0){
      #pragma unroll
      for (int r = 0; r < 4; r++){
        float yf = accf[r], yc = accc[r];
        s0 += yf; q0 += yf*yf; s1 += yc; q1 += yc*yc;
      }
    } else {
      int ebase = e0 + eh*16 + g*4;   // C row = (lane>>4)*4 + reg
      #pragma unroll
      for (int r = 0; r < 4; r++){
        float f  = sigmoidf_(accf[r]*sf + hf);
        float c2 = softplusf_(accc[r]*sc + hc);
        int a = sidx[ebase + r];
        atomicAdd(&meanacc[(size_t)a*64 + colf], f*c2);
      }
    }
  }

  if (PASS == 0){
    // block-reduce into LDS, then ONE partial row per block (no contended atomics)
    s0 += __shfl_xor(s0,16); s0 += __shfl_xor(s0,32);
    q0 += __shfl_xor(q0,16); q0 += __shfl_xor(q0,32);
    s1 += __shfl_xor(s1,16); s1 += __shfl_xor(s1,32);
    q1 += __shfl_xor(q1,16); q1 += __shfl_xor(q1,32);
    __syncthreads();
    float* scm = (float*)xb;   // 8 waves x 16 lanes x 4 values = 2048 floats
    if (g == 0)
      *(float4*)&scm[(wid*16 + r16)*4] = make_float4(s0, q0, s1, q1);
    __syncthreads();
    if (t < 256){
      int stat = t >> 7, colx = t & 127;
      int cqj = (colx & 63) >> 4, rj = colx & 15;
      int v = (colx < 64) ? stat : 2 + stat;
      float s = scm[((0*4+cqj)*16 + rj)*4 + v] + scm[((1*4+cqj)*16 + rj)*4 + v];
      partial[(size_t)blockIdx.x*256 + t] = s;   // [stat*128 + col]
    }
  }
}

// ---------------------------------------------------------------- BN finalize: scale/shift from stats
__global__ void bnfin_kernel(int nf, float invcnt,
                             const float* __restrict__ sum, const float* __restrict__ sq,
                             const float* __restrict__ g, const float* __restrict__ b,
                             float* __restrict__ scale, float* __restrict__ shift){
  int j = threadIdx.x;
  if (j < nf){
    float m = sum[j]*invcnt;
    float v = fmaxf(sq[j]*invcnt - m*m, 0.0f);
    float is = rsqrtf(v + 1e-5f);
    float s = g[j]*is;
    scale[j] = s;
    shift[j] = b[j] - m*s;
  }
}

// ---------------------------------------------------------------- mean = meanacc * recip, + stats over N
__global__ __launch_bounds__(256) void meanbn_stats(const float* __restrict__ recip,
                                                    float* __restrict__ meanacc,
                                                    float* __restrict__ partial){
  int t = threadIdx.x;
  float s = 0.f, q = 0.f;
  for (size_t idx = (size_t)blockIdx.x*256 + t; idx < (size_t)NATOM*64; idx += (size_t)gridDim.x*256){
    int n = (int)(idx >> 6);
    float v = meanacc[idx]*recip[n];
    meanacc[idx] = v;
    s += v; q += v*v;
  }
  __shared__ float red[256][2];
  red[t][0]=s; red[t][1]=q;
  __syncthreads();
  if (t < 64){
    for (int i=1;i<4;i++){ s += red[t+64*i][0]; q += red[t+64*i][1]; }
    partial[(size_t)blockIdx.x*128 + t]      = s;
    partial[(size_t)blockIdx.x*128 + 64 + t] = q;
  }
}

__global__ __launch_bounds__(256) void atom_update(float* __restrict__ atom,
                                                   const float* __restrict__ meanv,
                                                   const float* __restrict__ scale,
                                                   const float* __restrict__ shift){
  for (size_t idx = (size_t)blockIdx.x*256 + threadIdx.x; idx < (size_t)NATOM*64; idx += (size_t)gridDim.x*256){
    int j = (int)(idx & 63);
    atom[idx] = softplusf_(atom[idx] + meanv[idx]*scale[j] + shift[j]);
  }
}

// ---------------------------------------------------------------- gate MLP, pass 1: h = atom @ W1 + b1, stats
__global__ __launch_bounds__(256, 2) void gate_pass1(const float* __restrict__ atom,
                                                     const float* __restrict__ W1, const float* __restrict__ b1,
                                                     float* __restrict__ hbuf,
                                                     float* __restrict__ partial){
  __shared__ float As[256*65];   // 66.6 KB, +1 pad -> conflict-free
  __shared__ float Wl[64*16];    // 4 KB
  int t = threadIdx.x;
  *(float4*)&Wl[t*4] = ld4(W1 + t*4);
  const float* src = atom + (size_t)blockIdx.x*256*64;
  #pragma unroll
  for (int j = 0; j < 16; j++){
    int idx = j*256 + t;               // float4 index, fully coalesced
    float4 v = ld4(src + idx*4);
    int r = idx >> 4, c = (idx & 15)*4;
    float* d = &As[r*65 + c];
    d[0]=v.x; d[1]=v.y; d[2]=v.z; d[3]=v.w;
  }
  __syncthreads();
  float h[16];
  #pragma unroll
  for (int c=0;c<16;c++) h[c] = b1[c];
  const float* ar = &As[t*65];
  #pragma unroll 8
  for (int k=0;k<64;k++){
    float a = ar[k];
    #pragma unroll
    for (int c=0;c<16;c++) h[c] += a*Wl[k*16+c];
  }
  size_t n = (size_t)blockIdx.x*256 + t;
  #pragma unroll
  for (int c=0;c<16;c+=4)
    *(float4*)&hbuf[n*16+c] = make_float4(h[c],h[c+1],h[c+2],h[c+3]);
  // stats: wave reduce -> LDS -> one partial row per block
  __syncthreads();   // done reading As; safe to reuse
  #pragma unroll
  for (int c=0;c<16;c++){
    float v = h[c], v2 = h[c]*h[c];
    for (int off=32; off; off>>=1){ v += __shfl_down(v,off); v2 += __shfl_down(v2,off); }
    if ((t&63)==0){ As[(t>>6)*32 + c] = v; As[(t>>6)*32 + 16 + c] = v2; }
  }
  __syncthreads();
  if (t < 32)
    partial[(size_t)blockIdx.x*32 + t] = As[t] + As[32+t] + As[64+t] + As[96+t];
}

// ---------------------------------------------------------------- gate MLP, pass 2: BN+relu+W2, segment max
__global__ __launch_bounds__(256) void gate_pass2(const float* __restrict__ hbuf,
                                                  const float* __restrict__ scale, const float* __restrict__ shift,
                                                  const float* __restrict__ W2, const float* __restrict__ b2,
                                                  const int* __restrict__ cry,
                                                  float* __restrict__ gate, unsigned* __restrict__ gmaxk){
  int n = blockIdx.x*256 + threadIdx.x;
  float g = b2[0];
  #pragma unroll
  for (int c=0;c<16;c+=4){
    float4 hv = ld4(hbuf + (size_t)n*16 + c);
    float4 sc = ld4(scale + c), sh = ld4(shift + c), w = ld4(W2 + c);
    g += fmaxf(hv.x*sc.x+sh.x,0.f)*w.x + fmaxf(hv.y*sc.y+sh.y,0.f)*w.y
       + fmaxf(hv.z*sc.z+sh.z,0.f)*w.z + fmaxf(hv.w*sc.w+sh.w,0.f)*w.w;
  }
  gate[n] = g;
  atomicMax(&gmaxk[cry[n]], fkey(g));
}

__global__ __launch_bounds__(256) void gate_exp(float* __restrict__ gate,
                                                const float* __restrict__ aw,
                                                const int* __restrict__ cry,
                                                const unsigned* __restrict__ gmaxk,
                                                float* __restrict__ gsum){
  int n = blockIdx.x*256 + threadIdx.x;
  if (n < NATOM){
    int c = cry[n];
    float w = aw[n]*expf(gate[n] - fkeyinv(gmaxk[c]));
    gate[n] = w;
    atomicAdd(&gsum[c], w);
  }
}

__global__ __launch_bounds__(256) void crys_acc(const float* __restrict__ gate,
                                                const float* __restrict__ gsum,
                                                const int* __restrict__ cry,
                                                const float* __restrict__ atom,
                                                float* __restrict__ crys){
  for (size_t idx = (size_t)blockIdx.x*256 + threadIdx.x; idx < (size_t)NATOM*64; idx += (size_t)gridDim.x*256){
    int n = (int)(idx >> 6), j = (int)(idx & 63);
    int c = cry[n];
    float wn = gate[n] / (gsum[c] + 1e-13f);
    atomicAdd(&crys[(size_t)c*64 + j], wn*atom[idx]);
  }
}

// ---------------------------------------------------------------- fc head
__global__ __launch_bounds__(512) void fc_stats(const float* __restrict__ crys,
                                                const float* __restrict__ fcW, const float* __restrict__ fcb,
                                                float* __restrict__ hid,
                                                float* __restrict__ partial){
  __shared__ float Wl[64*128];  // 32 KB
  __shared__ float cb[64][16];  // 4 KB
  int t = threadIdx.x;
  for (int j = t; j < 64*32; j += 512)
    *(float4*)&Wl[j*4] = ld4(fcW + j*4);
  int cg = t & 31, cr = t >> 5;
  float4 bias = ld4(fcb + cg*4);
  float ssum[4] = {0,0,0,0}, ssq[4] = {0,0,0,0};
  for (int chunk = blockIdx.x; chunk < NCRY/16; chunk += gridDim.x){
    int c0 = chunk*16;
    __syncthreads();
    for (int j = t; j < 256; j += 512){
      int rr = j & 15, c = j >> 4;
      float4 v = ld4(crys + (size_t)(c0+rr)*64 + c*4);
      int k = c*4;
      cb[k][rr]=v.x; cb[k+1][rr]=v.y; cb[k+2][rr]=v.z; cb[k+3][rr]=v.w;
    }
    __syncthreads();
    float4 acc = bias;
    #pragma unroll 4
    for (int k=0;k<64;k++){
      float a = cb[k][cr];
      float4 w = *(float4*)&Wl[k*128 + cg*4];
      acc.x += a*w.x; acc.y += a*w.y; acc.z += a*w.z; acc.w += a*w.w;
    }
    *(float4*)&hid[(size_t)(c0+cr)*128 + cg*4] = acc;
    ssum[0]+=acc.x; ssum[1]+=acc.y; ssum[2]+=acc.z; ssum[3]+=acc.w;
    ssq[0]+=acc.x*acc.x; ssq[1]+=acc.y*acc.y; ssq[2]+=acc.z*acc.z; ssq[3]+=acc.w*acc.w;
  }
  __syncthreads();
  float* red = Wl;
  #pragma unroll
  for (int q=0;q<4;q++){ red[t*8+q] = ssum[q]; red[t*8+4+q] = ssq[q]; }
  __syncthreads();
  if (t < 128){
    int cgj = t >> 2, q = t & 3;
    float s = 0.f, sq = 0.f;
    for (int cri=0; cri<16; cri++){
      int tt = cri*32 + cgj;
      s  += red[tt*8+q];
      sq += red[tt*8+4+q];
    }
    partial[(size_t)blockIdx.x*256 + t]       = s;
    partial[(size_t)blockIdx.x*256 + 128 + t] = sq;
  }
}

__global__ __launch_bounds__(256) void out_kernel(const float* __restrict__ hid,
                                                  const float* __restrict__ scale, const float* __restrict__ shift,
                                                  const float* __restrict__ outW, const float* __restrict__ outb,
                                                  float* __restrict__ out){
  int c = blockIdx.x*4 + (threadIdx.x >> 6);
  int l = threadIdx.x & 63;
  float v = softplusf_(hid[(size_t)c*128 + l]*scale[l] + shift[l])*outW[l]
          + softplusf_(hid[(size_t)c*128 + 64 + l]*scale[64+l] + shift[64+l])*outW[64+l];
  for (int off=32; off; off >>= 1) v += __shfl_down(v, off);
  if (l == 0) out[c] = v + outb[0];
}

// ---------------------------------------------------------------- launch
extern "C" void kernel_launch(void* const* d_in, const int* in_sizes, int n_in,
                              void* d_out, int out_size, void* d_ws, size_t ws_size,
                              hipStream_t stream){
  const float* aw    = (const float*)d_in[0];
  const float* orig  = (const float*)d_in[1];
  const float* nbr   = (const float*)d_in[2];
  const int*   sidx  = (const int*)d_in[3];
  const int*   nidx  = (const int*)d_in[4];
  const int*   cry   = (const int*)d_in[5];
  const float* embW  = (const float*)d_in[6];
  const float* embB  = (const float*)d_in[7];
  const float* filtW = (const float*)d_in[8];
  const float* filtB = (const float*)d_in[9];
  const float* coreW = (const float*)d_in[10];
  const float* coreB = (const float*)d_in[11];
  const float* bnfg  = (const float*)d_in[12];
  const float* bnfb  = (const float*)d_in[13];
  const float* bncg  = (const float*)d_in[14];
  const float* bncb  = (const float*)d_in[15];
  const float* bnog  = (const float*)d_in[16];
  const float* bnob  = (const float*)d_in[17];
  const float* gW1   = (const float*)d_in[18];
  const float* gb1   = (const float*)d_in[19];
  const float* gbng  = (const float*)d_in[20];
  const float* gbnb  = (const float*)d_in[21];
  const float* gW2   = (const float*)d_in[22];
  const float* gb2   = (const float*)d_in[23];
  const float* fcW   = (const float*)d_in[24];
  const float* fcb   = (const float*)d_in[25];
  const float* fcbng = (const float*)d_in[26];
  const float* fcbnb = (const float*)d_in[27];
  const float* outW  = (const float*)d_in[28];
  const float* outb  = (const float*)d_in[29];
  float* out = (float*)d_out;

  float* ws      = (float*)d_ws;
  float* atom    = ws;                              // N*64
  float* meanacc = atom    + (size_t)NATOM*64;      // N*64  (reused as hbuf after MP)
  float* cnt     = meanacc + (size_t)NATOM*64;      // N
  float* gate    = cnt     + NATOM;                 // N
  float* gmaxk   = gate    + NATOM;                 // C
  float* gsum    = gmaxk   + NCRY;                  // C
  float* crys    = gsum    + NCRY;                  // C*64
  float* hid     = crys    + (size_t)NCRY*64;       // C*128
  float* stats   = hid     + (size_t)NCRY*128;      // 256
  float* scale   = stats   + 256;                   // 128
  float* shift   = scale   + 128;                   // 128
  short* wth     = (short*)(shift + 128);           // 3*128*160 shorts
  short* wtl     = wth + 3*128*160;                 // 3*128*160 shorts
  float* partial = (float*)(wtl + 3*128*160);       // 2048*256 floats (2 MB)
  (void)in_sizes; (void)n_in; (void)out_size; (void)ws_size;

  // prep: counts, W split/transpose, embedding
  hipMemsetAsync(cnt, 0, NATOM*sizeof(float), stream);
  cnt_kernel<<<2048, 256, 0, stream>>>(sidx, cnt);
  recip_kernel<<<NATOM/256, 256, 0, stream>>>(cnt);
  wprep<<<240, 256, 0, stream>>>(filtW, coreW, wth, wtl);
  embed_kernel<<<2048, 256, 0, stream>>>(orig, embW, embB, atom);

  // message-passing layers
  for (int i = 0; i < 3; ++i){
    const short* wthL = wth + (size_t)i*128*160;
    const short* wtlL = wtl + (size_t)i*128*160;
    const float* bf = filtB + i*64;
    const float* bc = coreB + i*64;
    edge_mfma<0><<<2048, 512, 0, stream>>>(atom, nbr, sidx, nidx, wthL, wtlL, bf, bc,
                                           nullptr, nullptr, partial, nullptr);
    colreduce<<<4, 256, 0, stream>>>(partial, stats, 2048, 256);   // stats[0..128)=sum, [128..256)=sq
    bnfin_kernel<<<1, 64, 0, stream>>>(64, 1.0f/MEDGE, stats,    stats+128,    bnfg+i*64, bnfb+i*64, scale,    shift);
    bnfin_kernel<<<1, 64, 0, stream>>>(64, 1.0f/MEDGE, stats+64, stats+128+64, bncg+i*64, bncb+i*64, scale+64, shift+64);
    hipMemsetAsync(meanacc, 0, (size_t)NATOM*64*sizeof(float), stream);
    edge_mfma<1><<<2048, 512, 0, stream>>>(atom, nbr, sidx, nidx, wthL, wtlL, bf, bc,
                                           scale, shift, nullptr, meanacc);
    meanbn_stats<<<2048, 256, 0, stream>>>(cnt, meanacc, partial);
    colreduce<<<2, 256, 0, stream>>>(partial, stats, 2048, 128);   // stats[0..64)=sum, [64..128)=sq
    bnfin_kernel<<<1, 64, 0, stream>>>(64, 1.0f/NATOM, stats, stats+64, bnog+i*64, bnob+i*64, scale, shift);
    atom_update<<<2048, 256, 0, stream>>>(atom, meanacc, scale, shift);
  }

  // gate MLP + BN + attention pooling   (hbuf reuses meanacc)
  float* hbuf = meanacc;
  gate_pass1<<<NATOM/256, 256, 0, stream>>>(atom, gW1, gb1, hbuf, partial);
  colreduce<<<1, 256, 0, stream>>>(partial, stats, NATOM/256, 32); // stats[0..16)=sum, [16..32)=sq
  bnfin_kernel<<<1, 16, 0, stream>>>(16, 1.0f/NATOM, stats, stats+16, gbng, gbnb, scale, shift);
  hipMemsetAsync(gmaxk, 0, NCRY*sizeof(unsigned), stream);
  gate_pass2<<<NATOM/256, 256, 0, stream>>>(hbuf, scale, shift, gW2, gb2, cry, gate, (unsigned*)gmaxk);
  hipMemsetAsync(gsum, 0, NCRY*sizeof(float), stream);
  gate_exp<<<NATOM/256, 256, 0, stream>>>(gate, aw, cry, (const unsigned*)gmaxk, gsum);
  hipMemsetAsync(crys, 0, (size_t)NCRY*64*sizeof(float), stream);
  crys_acc<<<4096, 256, 0, stream>>>(gate, gsum, cry, atom, crys);

  // fc head
  fc_stats<<<1024, 512, 0, stream>>>(crys, fcW, fcb, hid, partial);
  colreduce<<<4, 256, 0, stream>>>(partial, stats, 1024, 256);     // stats[0..128)=sum, [128..256)=sq
  bnfin_kernel<<<1, 128, 0, stream>>>(128, 1.0f/NCRY, stats, stats+128, fcbng, fcbnb, scale, shift);
  out_kernel<<<NCRY/4, 256, 0, stream>>>(hid, scale, shift, outW, outb, out);
}

// Round 5
// 3206.042 us; speedup vs baseline: 2.9641x; 1.1235x over previous
//
#include <hip/hip_runtime.h>
#include <cstdint>
#include <cstddef>

// Problem constants (from reference)
#define NATOM 262144
#define MEDGE 1048576
#define NCRY  32768
// ORIG=200, AF=64, NF=32, GH=16, H=128, NG=3

typedef __attribute__((ext_vector_type(8))) short short8v;   // 8 bf16 (4 VGPR)
typedef __attribute__((ext_vector_type(4))) float f32x4;     // MFMA acc

__device__ __forceinline__ float4 ld4(const float* p){ return *reinterpret_cast<const float4*>(p); }

__device__ __forceinline__ float softplusf_(float x){
  return fmaxf(x, 0.0f) + log1pf(expf(-fabsf(x)));
}
__device__ __forceinline__ float softplus_fast(float x){
  return fmaxf(x, 0.0f) + __logf(1.0f + __expf(-fabsf(x)));
}
__device__ __forceinline__ float sigmoid_fast(float y){
  return __builtin_amdgcn_rcpf(1.0f + __expf(-y));
}

__device__ __forceinline__ unsigned short rne_bf16(float f){
  unsigned u = __float_as_uint(f);
  unsigned r = u + 0x7FFFu + ((u >> 16) & 1u);
  return (unsigned short)(r >> 16);
}

// monotonic float<->uint key for atomicMax-based segment max
__device__ __forceinline__ unsigned fkey(float x){
  unsigned b = __float_as_uint(x);
  return (b & 0x80000000u) ? ~b : (b | 0x80000000u);
}
__device__ __forceinline__ float fkeyinv(unsigned k){
  unsigned b = (k & 0x80000000u) ? (k & 0x7fffffffu) : ~k;
  return __uint_as_float(b);
}

// ---------------------------------------------------------------- generic column reduce: out[c] = sum_b part[b*nc+c]
__global__ __launch_bounds__(256) void colreduce(const float* __restrict__ part, float* __restrict__ out,
                                                 int nb, int nc){
  __shared__ float red[4][64];
  int c64 = threadIdx.x & 63, sl = threadIdx.x >> 6;
  int c = blockIdx.x*64 + c64;
  float s = 0.f;
  if (c < nc)
    for (int b = sl; b < nb; b += 4) s += part[(size_t)b*nc + c];
  red[sl][c64] = s;
  __syncthreads();
  if (sl == 0 && c < nc)
    out[c] = red[0][c64] + red[1][c64] + red[2][c64] + red[3][c64];
}

// ---------------------------------------------------------------- counts
__global__ __launch_bounds__(256) void cnt_kernel(const int* __restrict__ sidx, float* __restrict__ cnt){
  for (int m = blockIdx.x*256 + threadIdx.x; m < MEDGE; m += gridDim.x*256)
    atomicAdd(&cnt[sidx[m]], 1.0f);
}
__global__ __launch_bounds__(256) void recip_kernel(float* __restrict__ cnt){
  int n = blockIdx.x*256 + threadIdx.x;
  if (n < NATOM) cnt[n] = 1.0f / fmaxf(cnt[n], 1.0f);
}

// ---------------------------------------------------------------- embedding: atom = orig @ embW + embB (+ bf16 hi/lo)
__global__ __launch_bounds__(256) void embed_kernel(const float* __restrict__ orig,
                                                    const float* __restrict__ W,
                                                    const float* __restrict__ b,
                                                    float* __restrict__ atom,
                                                    short* __restrict__ atom_h,
                                                    short* __restrict__ atom_l){
  __shared__ float Wl[200*64];     // 51.2 KB
  __shared__ float rb[200][16];    // 12.8 KB, transposed row tile
  int t = threadIdx.x;
  for (int j = t; j < 200*16; j += 256){
    int k = j >> 4, c4 = j & 15;
    *(float4*)&Wl[k*64 + c4*4] = ld4(W + k*64 + c4*4);
  }
  int cg = t & 15, r = t >> 4;
  float4 bias = ld4(b + cg*4);
  for (int chunk = blockIdx.x; chunk < NATOM/16; chunk += gridDim.x){
    int n0 = chunk*16;
    __syncthreads();
    for (int j = t; j < 50*16; j += 256){
      int rr = j & 15, c = j >> 4;
      float4 v = ld4(orig + (size_t)(n0+rr)*200 + c*4);
      int k = c*4;
      rb[k][rr]=v.x; rb[k+1][rr]=v.y; rb[k+2][rr]=v.z; rb[k+3][rr]=v.w;
    }
    __syncthreads();
    float4 acc = bias;
    #pragma unroll 4
    for (int k = 0; k < 200; ++k){
      float a = rb[k][r];
      float4 w = *(float4*)&Wl[k*64 + cg*4];
      acc.x += a*w.x; acc.y += a*w.y; acc.z += a*w.z; acc.w += a*w.w;
    }
    size_t base = (size_t)(n0+r)*64 + cg*4;
    *(float4*)&atom[base] = acc;
    unsigned ux = __float_as_uint(acc.x), uy = __float_as_uint(acc.y);
    unsigned uz = __float_as_uint(acc.z), uw = __float_as_uint(acc.w);
    unsigned hx = ux & 0xFFFF0000u, hy = uy & 0xFFFF0000u;
    unsigned hz = uz & 0xFFFF0000u, hw2 = uw & 0xFFFF0000u;
    uint2 hh = make_uint2((hx>>16) | hy, (hz>>16) | hw2);
    uint2 ll = make_uint2((unsigned)rne_bf16(acc.x - __uint_as_float(hx))
                        | ((unsigned)rne_bf16(acc.y - __uint_as_float(hy)) << 16),
                          (unsigned)rne_bf16(acc.z - __uint_as_float(hz))
                        | ((unsigned)rne_bf16(acc.w - __uint_as_float(hw2)) << 16));
    *(uint2*)&atom_h[base] = hh;
    *(uint2*)&atom_l[base] = ll;
  }
}

// ---------------------------------------------------------------- W prep: fused+transposed+split-bf16
__global__ __launch_bounds__(256) void wprep(const float* __restrict__ filtW, const float* __restrict__ coreW,
                                             short* __restrict__ Wth, short* __restrict__ Wtl){
  int idx = blockIdx.x*256 + threadIdx.x;   // 3*128*160 = 61440
  if (idx >= 3*128*160) return;
  int k = idx % 160; int rest = idx / 160; int c = rest & 127; int layer = rest >> 7;
  float w = (c < 64) ? filtW[((size_t)layer*160 + k)*64 + c] : coreW[((size_t)layer*160 + k)*64 + (c-64)];
  unsigned u = __float_as_uint(w);
  unsigned h = u & 0xFFFF0000u;
  Wth[idx] = (short)(h >> 16);
  Wtl[idx] = (short)rne_bf16(w - __uint_as_float(h));
}

// ---------------------------------------------------------------- edge GEMM via split-bf16 MFMA
// LDS frag-linear: chunk(eh,hilo,ks,lane) at ((eh*2+hilo)*5+ks)*1024 + lane*16 bytes
// staging writes row-fastest (conflict-light), compute reads lane-linear (conflict-free)

template<int PASS>
__global__ __launch_bounds__(512, 4) void edge_mfma(
    const short* __restrict__ atom_h, const short* __restrict__ atom_l,
    const float* __restrict__ nbr,
    const int* __restrict__ sidx, const int* __restrict__ nidx,
    const short* __restrict__ Wth, const short* __restrict__ Wtl,
    const float* __restrict__ bfp, const float* __restrict__ bcp,
    const float* __restrict__ scale, const float* __restrict__ shift,
    float* __restrict__ partial,
    float* __restrict__ meanacc)
{
  __shared__ uint4 xbv[1280];   // 20 KB
  int t = threadIdx.x;
  int lane = t & 63, wid = t >> 6;
  int eh = wid >> 2, cq = wid & 3;        // 2 edge-halves x 4 col-quarters
  int r16 = lane & 15, g = lane >> 4;
  int colf = cq*16 + r16, colc = colf + 64;

  short8v Bhf[5], Blf[5], Bhc[5], Blc[5];
  {
    const short* wfh = Wth + colf*160;
    const short* wch = Wth + colc*160;
    const short* wfl = Wtl + colf*160;
    const short* wcl = Wtl + colc*160;
    #pragma unroll
    for (int ks = 0; ks < 5; ks++){
      int o = ks*32 + g*8;
      Bhf[ks] = *(const short8v*)(wfh + o);
      Bhc[ks] = *(const short8v*)(wch + o);
      Blf[ks] = *(const short8v*)(wfl + o);
      Blc[ks] = *(const short8v*)(wcl + o);
    }
  }
  float bf = bfp[colf], bc = bcp[colf];
  float sf = 0.f, hf = 0.f, sc = 0.f, hc = 0.f;
  if (PASS == 1){ sf = scale[colf]; hf = shift[colf]; sc = scale[colc]; hc = shift[colc]; }
  float s0 = 0.f, q0 = 0.f, s1 = 0.f, q1 = 0.f;

  const uint4* ah_base = xbv + (eh*2+0)*5*64 + lane;
  const uint4* al_base = xbv + (eh*2+1)*5*64 + lane;

  for (int tile = blockIdx.x; tile < MEDGE/32; tile += gridDim.x){
    int e0 = tile*32;
    __syncthreads();
    // stage 32 edges: pure bf16 copy for atom chunks, on-the-fly split for fea chunks
    for (int j = t; j < 1280; j += 512){
      int e = j & 31, c = j >> 5;         // c: 0..39
      int hilo = (c >= 20) ? 1 : 0;
      int kcg = c - 20*hilo;              // 0..19
      uint4 v;
      if (kcg < 16){
        int an = (kcg < 8) ? sidx[e0+e] : nidx[e0+e];
        const short* src = (hilo ? atom_l : atom_h) + (size_t)an*64 + (kcg&7)*8;
        v = *(const uint4*)src;
      } else {
        const float* fsrc = nbr + (size_t)(e0+e)*32 + (kcg-16)*8;
        float4 f0 = ld4(fsrc), f1 = ld4(fsrc+4);
        float fv[8] = {f0.x,f0.y,f0.z,f0.w,f1.x,f1.y,f1.z,f1.w};
        unsigned w[4];
        #pragma unroll
        for (int i=0;i<4;i++){
          unsigned ua = __float_as_uint(fv[2*i]), ub = __float_as_uint(fv[2*i+1]);
          unsigned ha = ua & 0xFFFF0000u, hb = ub & 0xFFFF0000u;
          if (!hilo) w[i] = (ha>>16) | hb;
          else       w[i] = (unsigned)rne_bf16(fv[2*i]  -__uint_as_float(ha))
                          | ((unsigned)rne_bf16(fv[2*i+1]-__uint_as_float(hb))<<16);
        }
        v = make_uint4(w[0],w[1],w[2],w[3]);
      }
      int ehw = e >> 4, row = e & 15;
      int ks = kcg >> 2, kc = kcg & 3;
      xbv[((ehw*2+hilo)*5 + ks)*64 + kc*16 + row] = v;
    }
    __syncthreads();

    f32x4 accf = {bf,bf,bf,bf}, accc = {bc,bc,bc,bc};
    #pragma unroll
    for (int ks = 0; ks < 5; ks++){
      short8v ah = *(const short8v*)(ah_base + ks*64);
      short8v al = *(const short8v*)(al_base + ks*64);
      accf = __builtin_amdgcn_mfma_f32_16x16x32_bf16(ah, Bhf[ks], accf, 0, 0, 0);
      accc = __builtin_amdgcn_mfma_f32_16x16x32_bf16(ah, Bhc[ks], accc, 0, 0, 0);
      accf = __builtin_amdgcn_mfma_f32_16x16x32_bf16(al, Bhf[ks], accf, 0, 0, 0);
      accc = __builtin_amdgcn_mfma_f32_16x16x32_bf16(al, Bhc[ks], accc, 0, 0, 0);
      accf = __builtin_amdgcn_mfma_f32_16x16x32_bf16(ah, Blf[ks], accf, 0, 0, 0);
      accc = __builtin_amdgcn_mfma_f32_16x16x32_bf16(ah, Blc[ks], accc, 0, 0, 0);
    }

    if (PASS == 0){
      #pragma unroll
      for (int r = 0; r < 4; r++){
        float yf = accf[r], yc = accc[r];
        s0 += yf; q0 += yf*yf; s1 += yc; q1 += yc*yc;
      }
    } else {
      int ebase = e0 + eh*16 + g*4;   // C row = (lane>>4)*4 + reg
      #pragma unroll
      for (int r = 0; r < 4; r++){
        float f  = sigmoid_fast(accf[r]*sf + hf);
        float c2 = softplus_fast(accc[r]*sc + hc);
        int a = sidx[ebase + r];
        atomicAdd(&meanacc[(size_t)a*64 + colf], f*c2);
      }
    }
  }

  if (PASS == 0){
    // block-reduce into LDS, then ONE partial row per block (no contended atomics)
    s0 += __shfl_xor(s0,16); s0 += __shfl_xor(s0,32);
    q0 += __shfl_xor(q0,16); q0 += __shfl_xor(q0,32);
    s1 += __shfl_xor(s1,16); s1 += __shfl_xor(s1,32);
    q1 += __shfl_xor(q1,16); q1 += __shfl_xor(q1,32);
    __syncthreads();
    float* scm = (float*)xbv;   // 8 waves x 16 lanes x 4 values = 2048 floats
    if (g == 0)
      *(float4*)&scm[(wid*16 + r16)*4] = make_float4(s0, q0, s1, q1);
    __syncthreads();
    if (t < 256){
      int stat = t >> 7, colx = t & 127;
      int cqj = (colx & 63) >> 4, rj = colx & 15;
      int v = (colx < 64) ? stat : 2 + stat;
      float s = scm[((0*4+cqj)*16 + rj)*4 + v] + scm[((1*4+cqj)*16 + rj)*4 + v];
      partial[(size_t)blockIdx.x*256 + t] = s;   // [stat*128 + col]
    }
  }
}

// ---------------------------------------------------------------- BN finalize: scale/shift from stats
__global__ void bnfin_kernel(int nf, float invcnt,
                             const float* __restrict__ sum, const float* __restrict__ sq,
                             const float* __restrict__ g, const float* __restrict__ b,
                             float* __restrict__ scale, float* __restrict__ shift){
  int j = threadIdx.x;
  if (j < nf){
    float m = sum[j]*invcnt;
    float v = fmaxf(sq[j]*invcnt - m*m, 0.0f);
    float is = rsqrtf(v + 1e-5f);
    float s = g[j]*is;
    scale[j] = s;
    shift[j] = b[j] - m*s;
  }
}

// ---------------------------------------------------------------- stats of mean = meanacc * recip (read-only)
__global__ __launch_bounds__(256) void meanbn_stats(const float* __restrict__ recip,
                                                    const float* __restrict__ meanacc,
                                                    float* __restrict__ partial){
  int t = threadIdx.x;
  float s = 0.f, q = 0.f;
  for (size_t idx = (size_t)blockIdx.x*256 + t; idx < (size_t)NATOM*64; idx += (size_t)gridDim.x*256){
    int n = (int)(idx >> 6);
    float v = meanacc[idx]*recip[n];
    s += v; q += v*v;
  }
  __shared__ float red[256][2];
  red[t][0]=s; red[t][1]=q;
  __syncthreads();
  if (t < 64){
    for (int i=1;i<4;i++){ s += red[t+64*i][0]; q += red[t+64*i][1]; }
    partial[(size_t)blockIdx.x*128 + t]      = s;
    partial[(size_t)blockIdx.x*128 + 64 + t] = q;
  }
}

// atom = softplus(atom + (meanacc*recip)*scale + shift), + bf16 hi/lo refresh
__global__ __launch_bounds__(256) void atom_update(float* __restrict__ atom,
                                                   const float* __restrict__ meanacc,
                                                   const float* __restrict__ recip,
                                                   const float* __restrict__ scale,
                                                   const float* __restrict__ shift,
                                                   short* __restrict__ atom_h,
                                                   short* __restrict__ atom_l){
  for (size_t idx = (size_t)blockIdx.x*256 + threadIdx.x; idx < (size_t)NATOM*64; idx += (size_t)gridDim.x*256){
    int n = (int)(idx >> 6), j = (int)(idx & 63);
    float a = softplus_fast(atom[idx] + meanacc[idx]*recip[n]*scale[j] + shift[j]);
    atom[idx] = a;
    unsigned u = __float_as_uint(a), h = u & 0xFFFF0000u;
    atom_h[idx] = (short)(h >> 16);
    atom_l[idx] = (short)rne_bf16(a - __uint_as_float(h));
  }
}

// ---------------------------------------------------------------- gate MLP, pass 1: h = atom @ W1 + b1, stats
__global__ __launch_bounds__(256, 2) void gate_pass1(const float* __restrict__ atom,
                                                     const float* __restrict__ W1, const float* __restrict__ b1,
                                                     float* __restrict__ hbuf,
                                                     float* __restrict__ partial){
  __shared__ float As[256*65];   // 66.6 KB, +1 pad -> conflict-free
  __shared__ float Wl[64*16];    // 4 KB
  int t = threadIdx.x;
  *(float4*)&Wl[t*4] = ld4(W1 + t*4);
  const float* src = atom + (size_t)blockIdx.x*256*64;
  #pragma unroll
  for (int j = 0; j < 16; j++){
    int idx = j*256 + t;               // float4 index, fully coalesced
    float4 v = ld4(src + idx*4);
    int r = idx >> 4, c = (idx & 15)*4;
    float* d = &As[r*65 + c];
    d[0]=v.x; d[1]=v.y; d[2]=v.z; d[3]=v.w;
  }
  __syncthreads();
  float h[16];
  #pragma unroll
  for (int c=0;c<16;c++) h[c] = b1[c];
  const float* ar = &As[t*65];
  #pragma unroll 8
  for (int k=0;k<64;k++){
    float a = ar[k];
    #pragma unroll
    for (int c=0;c<16;c++) h[c] += a*Wl[k*16+c];
  }
  size_t n = (size_t)blockIdx.x*256 + t;
  #pragma unroll
  for (int c=0;c<16;c+=4)
    *(float4*)&hbuf[n*16+c] = make_float4(h[c],h[c+1],h[c+2],h[c+3]);
  // stats: wave reduce -> LDS -> one partial row per block
  __syncthreads();   // done reading As; safe to reuse
  #pragma unroll
  for (int c=0;c<16;c++){
    float v = h[c], v2 = h[c]*h[c];
    for (int off=32; off; off>>=1){ v += __shfl_down(v,off); v2 += __shfl_down(v2,off); }
    if ((t&63)==0){ As[(t>>6)*32 + c] = v; As[(t>>6)*32 + 16 + c] = v2; }
  }
  __syncthreads();
  if (t < 32)
    partial[(size_t)blockIdx.x*32 + t] = As[t] + As[32+t] + As[64+t] + As[96+t];
}

// ---------------------------------------------------------------- gate MLP, pass 2: BN+relu+W2, segment max
__global__ __launch_bounds__(256) void gate_pass2(const float* __restrict__ hbuf,
                                                  const float* __restrict__ scale, const float* __restrict__ shift,
                                                  const float* __restrict__ W2, const float* __restrict__ b2,
                                                  const int* __restrict__ cry,
                                                  float* __restrict__ gate, unsigned* __restrict__ gmaxk){
  int n = blockIdx.x*256 + threadIdx.x;
  float g = b2[0];
  #pragma unroll
  for (int c=0;c<16;c+=4){
    float4 hv = ld4(hbuf + (size_t)n*16 + c);
    float4 sc = ld4(scale + c), sh = ld4(shift + c), w = ld4(W2 + c);
    g += fmaxf(hv.x*sc.x+sh.x,0.f)*w.x + fmaxf(hv.y*sc.y+sh.y,0.f)*w.y
       + fmaxf(hv.z*sc.z+sh.z,0.f)*w.z + fmaxf(hv.w*sc.w+sh.w,0.f)*w.w;
  }
  gate[n] = g;
  atomicMax(&gmaxk[cry[n]], fkey(g));
}

__global__ __launch_bounds__(256) void gate_exp(float* __restrict__ gate,
                                                const float* __restrict__ aw,
                                                const int* __restrict__ cry,
                                                const unsigned* __restrict__ gmaxk,
                                                float* __restrict__ gsum){
  int n = blockIdx.x*256 + threadIdx.x;
  if (n < NATOM){
    int c = cry[n];
    float w = aw[n]*expf(gate[n] - fkeyinv(gmaxk[c]));
    gate[n] = w;
    atomicAdd(&gsum[c], w);
  }
}

__global__ __launch_bounds__(256) void crys_acc(const float* __restrict__ gate,
                                                const float* __restrict__ gsum,
                                                const int* __restrict__ cry,
                                                const float* __restrict__ atom,
                                                float* __restrict__ crys){
  for (size_t idx = (size_t)blockIdx.x*256 + threadIdx.x; idx < (size_t)NATOM*64; idx += (size_t)gridDim.x*256){
    int n = (int)(idx >> 6), j = (int)(idx & 63);
    int c = cry[n];
    float wn = gate[n] / (gsum[c] + 1e-13f);
    atomicAdd(&crys[(size_t)c*64 + j], wn*atom[idx]);
  }
}

// ---------------------------------------------------------------- fc head
__global__ __launch_bounds__(512) void fc_stats(const float* __restrict__ crys,
                                                const float* __restrict__ fcW, const float* __restrict__ fcb,
                                                float* __restrict__ hid,
                                                float* __restrict__ partial){
  __shared__ float Wl[64*128];  // 32 KB
  __shared__ float cb[64][16];  // 4 KB
  int t = threadIdx.x;
  for (int j = t; j < 64*32; j += 512)
    *(float4*)&Wl[j*4] = ld4(fcW + j*4);
  int cg = t & 31, cr = t >> 5;
  float4 bias = ld4(fcb + cg*4);
  float ssum[4] = {0,0,0,0}, ssq[4] = {0,0,0,0};
  for (int chunk = blockIdx.x; chunk < NCRY/16; chunk += gridDim.x){
    int c0 = chunk*16;
    __syncthreads();
    for (int j = t; j < 256; j += 512){
      int rr = j & 15, c = j >> 4;
      float4 v = ld4(crys + (size_t)(c0+rr)*64 + c*4);
      int k = c*4;
      cb[k][rr]=v.x; cb[k+1][rr]=v.y; cb[k+2][rr]=v.z; cb[k+3][rr]=v.w;
    }
    __syncthreads();
    float4 acc = bias;
    #pragma unroll 4
    for (int k=0;k<64;k++){
      float a = cb[k][cr];
      float4 w = *(float4*)&Wl[k*128 + cg*4];
      acc.x += a*w.x; acc.y += a*w.y; acc.z += a*w.z; acc.w += a*w.w;
    }
    *(float4*)&hid[(size_t)(c0+cr)*128 + cg*4] = acc;
    ssum[0]+=acc.x; ssum[1]+=acc.y; ssum[2]+=acc.z; ssum[3]+=acc.w;
    ssq[0]+=acc.x*acc.x; ssq[1]+=acc.y*acc.y; ssq[2]+=acc.z*acc.z; ssq[3]+=acc.w*acc.w;
  }
  __syncthreads();
  float* red = Wl;
  #pragma unroll
  for (int q=0;q<4;q++){ red[t*8+q] = ssum[q]; red[t*8+4+q] = ssq[q]; }
  __syncthreads();
  if (t < 128){
    int cgj = t >> 2, q = t & 3;
    float s = 0.f, sq = 0.f;
    for (int cri=0; cri<16; cri++){
      int tt = cri*32 + cgj;
      s  += red[tt*8+q];
      sq += red[tt*8+4+q];
    }
    partial[(size_t)blockIdx.x*256 + t]       = s;
    partial[(size_t)blockIdx.x*256 + 128 + t] = sq;
  }
}

__global__ __launch_bounds__(256) void out_kernel(const float* __restrict__ hid,
                                                  const float* __restrict__ scale, const float* __restrict__ shift,
                                                  const float* __restrict__ outW, const float* __restrict__ outb,
                                                  float* __restrict__ out){
  int c = blockIdx.x*4 + (threadIdx.x >> 6);
  int l = threadIdx.x & 63;
  float v = softplusf_(hid[(size_t)c*128 + l]*scale[l] + shift[l])*outW[l]
          + softplusf_(hid[(size_t)c*128 + 64 + l]*scale[64+l] + shift[64+l])*outW[64+l];
  for (int off=32; off; off >>= 1) v += __shfl_down(v, off);
  if (l == 0) out[c] = v + outb[0];
}

// ---------------------------------------------------------------- launch
extern "C" void kernel_launch(void* const* d_in, const int* in_sizes, int n_in,
                              void* d_out, int out_size, void* d_ws, size_t ws_size,
                              hipStream_t stream){
  const float* aw    = (const float*)d_in[0];
  const float* orig  = (const float*)d_in[1];
  const float* nbr   = (const float*)d_in[2];
  const int*   sidx  = (const int*)d_in[3];
  const int*   nidx  = (const int*)d_in[4];
  const int*   cry   = (const int*)d_in[5];
  const float* embW  = (const float*)d_in[6];
  const float* embB  = (const float*)d_in[7];
  const float* filtW = (const float*)d_in[8];
  const float* filtB = (const float*)d_in[9];
  const float* coreW = (const float*)d_in[10];
  const float* coreB = (const float*)d_in[11];
  const float* bnfg  = (const float*)d_in[12];
  const float* bnfb  = (const float*)d_in[13];
  const float* bncg  = (const float*)d_in[14];
  const float* bncb  = (const float*)d_in[15];
  const float* bnog  = (const float*)d_in[16];
  const float* bnob  = (const float*)d_in[17];
  const float* gW1   = (const float*)d_in[18];
  const float* gb1   = (const float*)d_in[19];
  const float* gbng  = (const float*)d_in[20];
  const float* gbnb  = (const float*)d_in[21];
  const float* gW2   = (const float*)d_in[22];
  const float* gb2   = (const float*)d_in[23];
  const float* fcW   = (const float*)d_in[24];
  const float* fcb   = (const float*)d_in[25];
  const float* fcbng = (const float*)d_in[26];
  const float* fcbnb = (const float*)d_in[27];
  const float* outW  = (const float*)d_in[28];
  const float* outb  = (const float*)d_in[29];
  float* out = (float*)d_out;

  float* ws      = (float*)d_ws;
  float* atom    = ws;                              // N*64
  float* meanacc = atom    + (size_t)NATOM*64;      // N*64  (reused as hbuf after MP)
  float* cnt     = meanacc + (size_t)NATOM*64;      // N
  float* gate    = cnt     + NATOM;                 // N
  float* gmaxk   = gate    + NATOM;                 // C
  float* gsum    = gmaxk   + NCRY;                  // C
  float* crys    = gsum    + NCRY;                  // C*64
  float* hid     = crys    + (size_t)NCRY*64;       // C*128
  float* stats   = hid     + (size_t)NCRY*128;      // 256
  float* scale   = stats   + 256;                   // 128
  float* shift   = scale   + 128;                   // 128
  short* wth     = (short*)(shift + 128);           // 3*128*160 shorts
  short* wtl     = wth + 3*128*160;                 // 3*128*160 shorts
  float* partial = (float*)(wtl + 3*128*160);       // 2048*256 floats (2 MB)
  short* atom_h  = (short*)(partial + 2048*256);    // N*64 shorts (33.5 MB)
  short* atom_l  = atom_h + (size_t)NATOM*64;       // N*64 shorts
  (void)in_sizes; (void)n_in; (void)out_size; (void)ws_size;

  // prep: counts, W split/transpose, embedding (+hi/lo)
  hipMemsetAsync(cnt, 0, NATOM*sizeof(float), stream);
  cnt_kernel<<<2048, 256, 0, stream>>>(sidx, cnt);
  recip_kernel<<<NATOM/256, 256, 0, stream>>>(cnt);
  wprep<<<240, 256, 0, stream>>>(filtW, coreW, wth, wtl);
  embed_kernel<<<2048, 256, 0, stream>>>(orig, embW, embB, atom, atom_h, atom_l);

  // message-passing layers
  for (int i = 0; i < 3; ++i){
    const short* wthL = wth + (size_t)i*128*160;
    const short* wtlL = wtl + (size_t)i*128*160;
    const float* bf = filtB + i*64;
    const float* bc = coreB + i*64;
    edge_mfma<0><<<2048, 512, 0, stream>>>(atom_h, atom_l, nbr, sidx, nidx, wthL, wtlL, bf, bc,
                                           nullptr, nullptr, partial, nullptr);
    colreduce<<<4, 256, 0, stream>>>(partial, stats, 2048, 256);   // stats[0..128)=sum, [128..256)=sq
    bnfin_kernel<<<1, 64, 0, stream>>>(64, 1.0f/MEDGE, stats,    stats+128,    bnfg+i*64, bnfb+i*64, scale,    shift);
    bnfin_kernel<<<1, 64, 0, stream>>>(64, 1.0f/MEDGE, stats+64, stats+128+64, bncg+i*64, bncb+i*64, scale+64, shift+64);
    hipMemsetAsync(meanacc, 0, (size_t)NATOM*64*sizeof(float), stream);
    edge_mfma<1><<<2048, 512, 0, stream>>>(atom_h, atom_l, nbr, sidx, nidx, wthL, wtlL, bf, bc,
                                           scale, shift, nullptr, meanacc);
    meanbn_stats<<<2048, 256, 0, stream>>>(cnt, meanacc, partial);
    colreduce<<<2, 256, 0, stream>>>(partial, stats, 2048, 128);   // stats[0..64)=sum, [64..128)=sq
    bnfin_kernel<<<1, 64, 0, stream>>>(64, 1.0f/NATOM, stats, stats+64, bnog+i*64, bnob+i*64, scale, shift);
    atom_update<<<2048, 256, 0, stream>>>(atom, meanacc, cnt, scale, shift, atom_h, atom_l);
  }

  // gate MLP + BN + attention pooling   (hbuf reuses meanacc)
  float* hbuf = meanacc;
  gate_pass1<<<NATOM/256, 256, 0, stream>>>(atom, gW1, gb1, hbuf, partial);
  colreduce<<<1, 256, 0, stream>>>(partial, stats, NATOM/256, 32); // stats[0..16)=sum, [16..32)=sq
  bnfin_kernel<<<1, 16, 0, stream>>>(16, 1.0f/NATOM, stats, stats+16, gbng, gbnb, scale, shift);
  hipMemsetAsync(gmaxk, 0, NCRY*sizeof(unsigned), stream);
  gate_pass2<<<NATOM/256, 256, 0, stream>>>(hbuf, scale, shift, gW2, gb2, cry, gate, (unsigned*)gmaxk);
  hipMemsetAsync(gsum, 0, NCRY*sizeof(float), stream);
  gate_exp<<<NATOM/256, 256, 0, stream>>>(gate, aw, cry, (const unsigned*)gmaxk, gsum);
  hipMemsetAsync(crys, 0, (size_t)NCRY*64*sizeof(float), stream);
  crys_acc<<<4096, 256, 0, stream>>>(gate, gsum, cry, atom, crys);

  // fc head
  fc_stats<<<1024, 512, 0, stream>>>(crys, fcW, fcb, hid, partial);
  colreduce<<<4, 256, 0, stream>>>(partial, stats, 1024, 256);     // stats[0..128)=sum, [128..256)=sq
  bnfin_kernel<<<1, 128, 0, stream>>>(128, 1.0f/NCRY, stats, stats+128, fcbng, fcbnb, scale, shift);
  out_kernel<<<NCRY/4, 256, 0, stream>>>(hid, scale, shift, outW, outb, out);
}

// Round 6
// 2782.818 us; speedup vs baseline: 3.4149x; 1.1521x over previous
//
#include <hip/hip_runtime.h>
#include <cstdint>
#include <cstddef>

// Problem constants (from reference)
#define NATOM 262144
#define MEDGE 1048576
#define NCRY  32768
// ORIG=200, AF=64, NF=32, GH=16, H=128, NG=3

typedef __attribute__((ext_vector_type(8))) short short8v;   // 8 bf16 (4 VGPR)
typedef __attribute__((ext_vector_type(4))) float f32x4;     // MFMA acc

__device__ __forceinline__ float4 ld4(const float* p){ return *reinterpret_cast<const float4*>(p); }

__device__ __forceinline__ float softplusf_(float x){
  return fmaxf(x, 0.0f) + log1pf(expf(-fabsf(x)));
}
__device__ __forceinline__ float softplus_fast(float x){
  return fmaxf(x, 0.0f) + __logf(1.0f + __expf(-fabsf(x)));
}
__device__ __forceinline__ float sigmoid_fast(float y){
  return __builtin_amdgcn_rcpf(1.0f + __expf(-y));
}

__device__ __forceinline__ unsigned short rne_bf16(float f){
  unsigned u = __float_as_uint(f);
  unsigned r = u + 0x7FFFu + ((u >> 16) & 1u);
  return (unsigned short)(r >> 16);
}
__device__ __forceinline__ float bfu(short s){
  return __uint_as_float(((unsigned)(unsigned short)s) << 16);
}

// monotonic float<->uint key for atomicMax-based segment max
__device__ __forceinline__ unsigned fkey(float x){
  unsigned b = __float_as_uint(x);
  return (b & 0x80000000u) ? ~b : (b | 0x80000000u);
}
__device__ __forceinline__ float fkeyinv(unsigned k){
  unsigned b = (k & 0x80000000u) ? (k & 0x7fffffffu) : ~k;
  return __uint_as_float(b);
}

// async global->LDS 16B copy (dest: wave-uniform base + lane*16 implicit)
__device__ __forceinline__ void gll16(const void* g, void* l){
  __builtin_amdgcn_global_load_lds((const __attribute__((address_space(1))) unsigned*)g,
                                   (__attribute__((address_space(3))) unsigned*)l, 16, 0, 0);
}

// ---------------------------------------------------------------- generic column reduce
__global__ __launch_bounds__(256) void colreduce(const float* __restrict__ part, float* __restrict__ out,
                                                 int nb, int nc){
  __shared__ float red[4][64];
  int c64 = threadIdx.x & 63, sl = threadIdx.x >> 6;
  int c = blockIdx.x*64 + c64;
  float s = 0.f;
  if (c < nc)
    for (int b = sl; b < nb; b += 4) s += part[(size_t)b*nc + c];
  red[sl][c64] = s;
  __syncthreads();
  if (sl == 0 && c < nc)
    out[c] = red[0][c64] + red[1][c64] + red[2][c64] + red[3][c64];
}

// ---------------------------------------------------------------- counts
__global__ __launch_bounds__(256) void cnt_kernel(const int* __restrict__ sidx, float* __restrict__ cnt){
  for (int m = blockIdx.x*256 + threadIdx.x; m < MEDGE; m += gridDim.x*256)
    atomicAdd(&cnt[sidx[m]], 1.0f);
}
__global__ __launch_bounds__(256) void recip_kernel(float* __restrict__ cnt){
  int n = blockIdx.x*256 + threadIdx.x;
  if (n < NATOM) cnt[n] = 1.0f / fmaxf(cnt[n], 1.0f);
}

// ---------------------------------------------------------------- nbr_fea -> bf16 (rne, hi only)
__global__ __launch_bounds__(256) void nbrprep(const float* __restrict__ nbr, short* __restrict__ nbr_h){
  for (size_t ch = (size_t)blockIdx.x*256 + threadIdx.x; ch < (size_t)MEDGE*32/8; ch += (size_t)gridDim.x*256){
    const float* s = nbr + ch*8;
    float4 a = ld4(s), b = ld4(s+4);
    float fv[8] = {a.x,a.y,a.z,a.w,b.x,b.y,b.z,b.w};
    unsigned w[4];
    #pragma unroll
    for (int i=0;i<4;i++)
      w[i] = (unsigned)rne_bf16(fv[2*i]) | ((unsigned)rne_bf16(fv[2*i+1]) << 16);
    *(uint4*)(nbr_h + ch*8) = make_uint4(w[0],w[1],w[2],w[3]);
  }
}

// ---------------------------------------------------------------- embedding: atom = orig @ embW + embB -> bf16 hi/lo
__global__ __launch_bounds__(256) void embed_kernel(const float* __restrict__ orig,
                                                    const float* __restrict__ W,
                                                    const float* __restrict__ b,
                                                    short* __restrict__ atom_h,
                                                    short* __restrict__ atom_l){
  __shared__ float Wl[200*64];
  __shared__ float rb[200][16];
  int t = threadIdx.x;
  for (int j = t; j < 200*16; j += 256){
    int k = j >> 4, c4 = j & 15;
    *(float4*)&Wl[k*64 + c4*4] = ld4(W + k*64 + c4*4);
  }
  int cg = t & 15, r = t >> 4;
  float4 bias = ld4(b + cg*4);
  for (int chunk = blockIdx.x; chunk < NATOM/16; chunk += gridDim.x){
    int n0 = chunk*16;
    __syncthreads();
    for (int j = t; j < 50*16; j += 256){
      int rr = j & 15, c = j >> 4;
      float4 v = ld4(orig + (size_t)(n0+rr)*200 + c*4);
      int k = c*4;
      rb[k][rr]=v.x; rb[k+1][rr]=v.y; rb[k+2][rr]=v.z; rb[k+3][rr]=v.w;
    }
    __syncthreads();
    float4 acc = bias;
    #pragma unroll 4
    for (int k = 0; k < 200; ++k){
      float a = rb[k][r];
      float4 w = *(float4*)&Wl[k*64 + cg*4];
      acc.x += a*w.x; acc.y += a*w.y; acc.z += a*w.z; acc.w += a*w.w;
    }
    size_t base = (size_t)(n0+r)*64 + cg*4;
    unsigned ux = __float_as_uint(acc.x), uy = __float_as_uint(acc.y);
    unsigned uz = __float_as_uint(acc.z), uw = __float_as_uint(acc.w);
    unsigned hx = ux & 0xFFFF0000u, hy = uy & 0xFFFF0000u;
    unsigned hz = uz & 0xFFFF0000u, hw2 = uw & 0xFFFF0000u;
    uint2 hh = make_uint2((hx>>16) | hy, (hz>>16) | hw2);
    uint2 ll = make_uint2((unsigned)rne_bf16(acc.x - __uint_as_float(hx))
                        | ((unsigned)rne_bf16(acc.y - __uint_as_float(hy)) << 16),
                          (unsigned)rne_bf16(acc.z - __uint_as_float(hz))
                        | ((unsigned)rne_bf16(acc.w - __uint_as_float(hw2)) << 16));
    *(uint2*)&atom_h[base] = hh;
    *(uint2*)&atom_l[base] = ll;
  }
}

// ---------------------------------------------------------------- W prep: fused+transposed+split-bf16
__global__ __launch_bounds__(256) void wprep(const float* __restrict__ filtW, const float* __restrict__ coreW,
                                             short* __restrict__ Wth, short* __restrict__ Wtl){
  int idx = blockIdx.x*256 + threadIdx.x;   // 3*128*160 = 61440
  if (idx >= 3*128*160) return;
  int k = idx % 160; int rest = idx / 160; int c = rest & 127; int layer = rest >> 7;
  float w = (c < 64) ? filtW[((size_t)layer*160 + k)*64 + c] : coreW[((size_t)layer*160 + k)*64 + (c-64)];
  unsigned u = __float_as_uint(w);
  unsigned h = u & 0xFFFF0000u;
  Wth[idx] = (short)(h >> 16);
  Wtl[idx] = (short)rne_bf16(w - __uint_as_float(h));
}

// ---------------------------------------------------------------- edge GEMM: async gll pipeline, TILE=64
// LDS buffer: [36 columns][64 edges] of 16B. columns: 0-7 self_h, 8-15 nbr_h, 16-19 fea_h,
//                                              20-27 self_l, 28-35 nbr_l  (fea lo dropped)
#define NT_PER_BLK 8

__device__ __forceinline__ void stage_tile(uint4* dst, int tile, int se, int ne, int wid, int lane,
                                           const short* __restrict__ atom_h, const short* __restrict__ atom_l,
                                           const short* __restrict__ nbr_h){
  const short* fh = nbr_h + (size_t)(tile*64 + lane)*32;
  const short* sh = atom_h + (size_t)se*64;
  const short* nh = atom_h + (size_t)ne*64;
  const short* sl = atom_l + (size_t)se*64;
  const short* nl = atom_l + (size_t)ne*64;
  #pragma unroll
  for (int i = 0; i < 9; ++i){
    int c = wid*9 + i;
    const short* src = (c < 8)  ? sh + c*8
                     : (c < 16) ? nh + (c-8)*8
                     : (c < 20) ? fh + (c-16)*8
                     : (c < 28) ? sl + (c-20)*8
                     :            nl + (c-28)*8;
    gll16(src, &dst[c*64]);
  }
}

#define MFMA_B(A,B,ACC) ACC = __builtin_amdgcn_mfma_f32_16x16x32_bf16(A, B, ACC, 0, 0, 0)

template<int PASS>
__global__ __launch_bounds__(256) void edge_mfma(
    const short* __restrict__ atom_h, const short* __restrict__ atom_l,
    const short* __restrict__ nbr_h,
    const int* __restrict__ sidx, const int* __restrict__ nidx,
    const short* __restrict__ Wth, const short* __restrict__ Wtl,
    const float* __restrict__ bfp, const float* __restrict__ bcp,
    const float* __restrict__ scale, const float* __restrict__ shift,
    float* __restrict__ partial,
    float* __restrict__ meanacc)
{
  __shared__ uint4 xb[2][36*64];   // 2 x 36 KB
  int t = threadIdx.x, lane = t & 63, wid = t >> 6;   // 4 waves
  int r16 = lane & 15, g = lane >> 4;
  int colf = wid*16 + r16, colc = colf + 64;

  short8v Bhf[5], Blf[5], Bhc[5], Blc[5];
  {
    const short* wfh = Wth + colf*160;
    const short* wch = Wth + colc*160;
    const short* wfl = Wtl + colf*160;
    const short* wcl = Wtl + colc*160;
    #pragma unroll
    for (int ks = 0; ks < 5; ks++){
      int o = ks*32 + g*8;
      Bhf[ks] = *(const short8v*)(wfh + o);
      Bhc[ks] = *(const short8v*)(wch + o);
      Blf[ks] = *(const short8v*)(wfl + o);
      Blc[ks] = *(const short8v*)(wcl + o);
    }
  }
  float bfv = bfp[colf], bcv = bcp[colf];
  float sf = 0.f, hf = 0.f, sc = 0.f, hc = 0.f;
  if (PASS == 1){ sf = scale[colf]; hf = shift[colf]; sc = scale[colc]; hc = shift[colc]; }
  float s0 = 0.f, q0 = 0.f, s1 = 0.f, q1 = 0.f;

  int tile0 = blockIdx.x * NT_PER_BLK;
  int se, ne;
  { int e = tile0*64 + lane; se = sidx[e]; ne = nidx[e]; }
  stage_tile(xb[0], tile0, se, ne, wid, lane, atom_h, atom_l, nbr_h);
  { int e = (tile0+1)*64 + lane; se = sidx[e]; ne = nidx[e]; }

  for (int tt = 0; tt < NT_PER_BLK; ++tt){
    const uint4* buf = xb[tt & 1];
    if (tt+1 < NT_PER_BLK){
      stage_tile(xb[(tt+1)&1], tile0+tt+1, se, ne, wid, lane, atom_h, atom_l, nbr_h);
      if (tt+2 < NT_PER_BLK){ int e = (tile0+tt+2)*64 + lane; se = sidx[e]; ne = nidx[e]; }
    }
    __builtin_amdgcn_sched_barrier(0);
    if (tt+2 < NT_PER_BLK)      asm volatile("s_waitcnt vmcnt(11)" ::: "memory");
    else if (tt+1 < NT_PER_BLK) asm volatile("s_waitcnt vmcnt(9)" ::: "memory");
    else                        asm volatile("s_waitcnt vmcnt(0)" ::: "memory");
    __builtin_amdgcn_sched_barrier(0);
    __builtin_amdgcn_s_barrier();
    __builtin_amdgcn_sched_barrier(0);

    int e0 = (tile0+tt)*64;
    #pragma unroll
    for (int hp = 0; hp < 2; ++hp){
      f32x4 accf0 = {bfv,bfv,bfv,bfv}, accc0 = {bcv,bcv,bcv,bcv};
      f32x4 accf1 = {bfv,bfv,bfv,bfv}, accc1 = {bcv,bcv,bcv,bcv};
      #pragma unroll
      for (int ks = 0; ks < 5; ++ks){
        int ci = (ks*4 + g)*64 + r16;
        short8v ah0 = *(const short8v*)&buf[ci + (hp*2+0)*16];
        short8v ah1 = *(const short8v*)&buf[ci + (hp*2+1)*16];
        MFMA_B(ah0, Bhf[ks], accf0); MFMA_B(ah1, Bhf[ks], accf1);
        MFMA_B(ah0, Bhc[ks], accc0); MFMA_B(ah1, Bhc[ks], accc1);
        MFMA_B(ah0, Blf[ks], accf0); MFMA_B(ah1, Blf[ks], accf1);
        MFMA_B(ah0, Blc[ks], accc0); MFMA_B(ah1, Blc[ks], accc1);
        if (ks < 4){
          int cl = (20 + ks*4 + g)*64 + r16;
          short8v al0 = *(const short8v*)&buf[cl + (hp*2+0)*16];
          short8v al1 = *(const short8v*)&buf[cl + (hp*2+1)*16];
          MFMA_B(al0, Bhf[ks], accf0); MFMA_B(al1, Bhf[ks], accf1);
          MFMA_B(al0, Bhc[ks], accc0); MFMA_B(al1, Bhc[ks], accc1);
        }
      }
      if (PASS == 0){
        #pragma unroll
        for (int r = 0; r < 4; r++){
          float a0 = accf0[r], a1 = accf1[r], c0 = accc0[r], c1 = accc1[r];
          s0 += a0 + a1; q0 += a0*a0 + a1*a1;
          s1 += c0 + c1; q1 += c0*c0 + c1*c1;
        }
      } else {
        int eb0 = e0 + (hp*2+0)*16 + g*4;
        int eb1 = e0 + (hp*2+1)*16 + g*4;
        #pragma unroll
        for (int r = 0; r < 4; r++){
          float f0 = sigmoid_fast(accf0[r]*sf + hf);
          float p0 = softplus_fast(accc0[r]*sc + hc);
          atomicAdd(&meanacc[(size_t)sidx[eb0 + r]*64 + colf], f0*p0);
          float f1 = sigmoid_fast(accf1[r]*sf + hf);
          float p1 = softplus_fast(accc1[r]*sc + hc);
          atomicAdd(&meanacc[(size_t)sidx[eb1 + r]*64 + colf], f1*p1);
        }
      }
    }
    __builtin_amdgcn_sched_barrier(0);
    __builtin_amdgcn_s_barrier();
    __builtin_amdgcn_sched_barrier(0);
  }

  if (PASS == 0){
    s0 += __shfl_xor(s0,16); s0 += __shfl_xor(s0,32);
    q0 += __shfl_xor(q0,16); q0 += __shfl_xor(q0,32);
    s1 += __shfl_xor(s1,16); s1 += __shfl_xor(s1,32);
    q1 += __shfl_xor(q1,16); q1 += __shfl_xor(q1,32);
    __syncthreads();
    float* scm = (float*)&xb[0][0];
    if (g == 0)
      *(float4*)&scm[(wid*16 + r16)*4] = make_float4(s0, q0, s1, q1);
    __syncthreads();
    {
      int stat = t >> 7, colx = t & 127;
      int isc = (colx >= 64) ? 1 : 0;
      int cc = colx & 63;
      int v = isc*2 + stat;
      partial[(size_t)blockIdx.x*256 + t] = scm[((cc>>4)*16 + (cc&15))*4 + v];
    }
  }
}

// ---------------------------------------------------------------- BN finalize
__global__ void bnfin_kernel(int nf, float invcnt,
                             const float* __restrict__ sum, const float* __restrict__ sq,
                             const float* __restrict__ g, const float* __restrict__ b,
                             float* __restrict__ scale, float* __restrict__ shift){
  int j = threadIdx.x;
  if (j < nf){
    float m = sum[j]*invcnt;
    float v = fmaxf(sq[j]*invcnt - m*m, 0.0f);
    float is = rsqrtf(v + 1e-5f);
    float s = g[j]*is;
    scale[j] = s;
    shift[j] = b[j] - m*s;
  }
}

// ---------------------------------------------------------------- stats of mean = meanacc * recip
__global__ __launch_bounds__(256) void meanbn_stats(const float* __restrict__ recip,
                                                    const float* __restrict__ meanacc,
                                                    float* __restrict__ partial){
  int t = threadIdx.x;
  float s = 0.f, q = 0.f;
  for (size_t idx = (size_t)blockIdx.x*256 + t; idx < (size_t)NATOM*64; idx += (size_t)gridDim.x*256){
    int n = (int)(idx >> 6);
    float v = meanacc[idx]*recip[n];
    s += v; q += v*v;
  }
  __shared__ float red[256][2];
  red[t][0]=s; red[t][1]=q;
  __syncthreads();
  if (t < 64){
    for (int i=1;i<4;i++){ s += red[t+64*i][0]; q += red[t+64*i][1]; }
    partial[(size_t)blockIdx.x*128 + t]      = s;
    partial[(size_t)blockIdx.x*128 + 64 + t] = q;
  }
}

// atom = softplus(atom + (meanacc*recip)*scale + shift), stored as bf16 hi/lo
__global__ __launch_bounds__(256) void atom_update(short* __restrict__ atom_h,
                                                   short* __restrict__ atom_l,
                                                   const float* __restrict__ meanacc,
                                                   const float* __restrict__ recip,
                                                   const float* __restrict__ scale,
                                                   const float* __restrict__ shift){
  for (size_t idx = (size_t)blockIdx.x*256 + threadIdx.x; idx < (size_t)NATOM*64; idx += (size_t)gridDim.x*256){
    int n = (int)(idx >> 6), j = (int)(idx & 63);
    float prev = bfu(atom_h[idx]) + bfu(atom_l[idx]);
    float a = softplus_fast(prev + meanacc[idx]*recip[n]*scale[j] + shift[j]);
    unsigned u = __float_as_uint(a), h = u & 0xFFFF0000u;
    atom_h[idx] = (short)(h >> 16);
    atom_l[idx] = (short)rne_bf16(a - __uint_as_float(h));
  }
}

// ---------------------------------------------------------------- gate MLP, pass 1
__global__ __launch_bounds__(256, 2) void gate_pass1(const short* __restrict__ atom_h,
                                                     const short* __restrict__ atom_l,
                                                     const float* __restrict__ W1, const float* __restrict__ b1,
                                                     float* __restrict__ hbuf,
                                                     float* __restrict__ partial){
  __shared__ float As[256*65];   // 66.6 KB
  __shared__ float Wl[64*16];
  int t = threadIdx.x;
  *(float4*)&Wl[t*4] = ld4(W1 + t*4);
  const short* hsrc = atom_h + (size_t)blockIdx.x*256*64;
  const short* lsrc = atom_l + (size_t)blockIdx.x*256*64;
  #pragma unroll
  for (int j = 0; j < 8; j++){
    int idx = j*256 + t;               // 8-element chunk, coalesced
    uint4 hv = *(const uint4*)(hsrc + idx*8);
    uint4 lv = *(const uint4*)(lsrc + idx*8);
    int r = idx >> 3, c = (idx & 7)*8;
    float* d = &As[r*65 + c];
    unsigned hw[4] = {hv.x,hv.y,hv.z,hv.w}, lw[4] = {lv.x,lv.y,lv.z,lv.w};
    #pragma unroll
    for (int i = 0; i < 4; i++){
      d[2*i]   = __uint_as_float(hw[i] << 16)          + __uint_as_float(lw[i] << 16);
      d[2*i+1] = __uint_as_float(hw[i] & 0xFFFF0000u)  + __uint_as_float(lw[i] & 0xFFFF0000u);
    }
  }
  __syncthreads();
  float h[16];
  #pragma unroll
  for (int c=0;c<16;c++) h[c] = b1[c];
  const float* ar = &As[t*65];
  #pragma unroll 8
  for (int k=0;k<64;k++){
    float a = ar[k];
    #pragma unroll
    for (int c=0;c<16;c++) h[c] += a*Wl[k*16+c];
  }
  size_t n = (size_t)blockIdx.x*256 + t;
  #pragma unroll
  for (int c=0;c<16;c+=4)
    *(float4*)&hbuf[n*16+c] = make_float4(h[c],h[c+1],h[c+2],h[c+3]);
  __syncthreads();
  #pragma unroll
  for (int c=0;c<16;c++){
    float v = h[c], v2 = h[c]*h[c];
    for (int off=32; off; off>>=1){ v += __shfl_down(v,off); v2 += __shfl_down(v2,off); }
    if ((t&63)==0){ As[(t>>6)*32 + c] = v; As[(t>>6)*32 + 16 + c] = v2; }
  }
  __syncthreads();
  if (t < 32)
    partial[(size_t)blockIdx.x*32 + t] = As[t] + As[32+t] + As[64+t] + As[96+t];
}

// ---------------------------------------------------------------- gate MLP, pass 2
__global__ __launch_bounds__(256) void gate_pass2(const float* __restrict__ hbuf,
                                                  const float* __restrict__ scale, const float* __restrict__ shift,
                                                  const float* __restrict__ W2, const float* __restrict__ b2,
                                                  const int* __restrict__ cry,
                                                  float* __restrict__ gate, unsigned* __restrict__ gmaxk){
  int n = blockIdx.x*256 + threadIdx.x;
  float g = b2[0];
  #pragma unroll
  for (int c=0;c<16;c+=4){
    float4 hv = ld4(hbuf + (size_t)n*16 + c);
    float4 sc = ld4(scale + c), sh = ld4(shift + c), w = ld4(W2 + c);
    g += fmaxf(hv.x*sc.x+sh.x,0.f)*w.x + fmaxf(hv.y*sc.y+sh.y,0.f)*w.y
       + fmaxf(hv.z*sc.z+sh.z,0.f)*w.z + fmaxf(hv.w*sc.w+sh.w,0.f)*w.w;
  }
  gate[n] = g;
  atomicMax(&gmaxk[cry[n]], fkey(g));
}

__global__ __launch_bounds__(256) void gate_exp(float* __restrict__ gate,
                                                const float* __restrict__ aw,
                                                const int* __restrict__ cry,
                                                const unsigned* __restrict__ gmaxk,
                                                float* __restrict__ gsum){
  int n = blockIdx.x*256 + threadIdx.x;
  if (n < NATOM){
    int c = cry[n];
    float w = aw[n]*expf(gate[n] - fkeyinv(gmaxk[c]));
    gate[n] = w;
    atomicAdd(&gsum[c], w);
  }
}

__global__ __launch_bounds__(256) void crys_acc(const float* __restrict__ gate,
                                                const float* __restrict__ gsum,
                                                const int* __restrict__ cry,
                                                const short* __restrict__ atom_h,
                                                const short* __restrict__ atom_l,
                                                float* __restrict__ crys){
  for (size_t idx = (size_t)blockIdx.x*256 + threadIdx.x; idx < (size_t)NATOM*64; idx += (size_t)gridDim.x*256){
    int n = (int)(idx >> 6), j = (int)(idx & 63);
    int c = cry[n];
    float wn = gate[n] / (gsum[c] + 1e-13f);
    float a = bfu(atom_h[idx]) + bfu(atom_l[idx]);
    atomicAdd(&crys[(size_t)c*64 + j], wn*a);
  }
}

// ---------------------------------------------------------------- fc head
__global__ __launch_bounds__(512) void fc_stats(const float* __restrict__ crys,
                                                const float* __restrict__ fcW, const float* __restrict__ fcb,
                                                float* __restrict__ hid,
                                                float* __restrict__ partial){
  __shared__ float Wl[64*128];
  __shared__ float cb[64][16];
  int t = threadIdx.x;
  for (int j = t; j < 64*32; j += 512)
    *(float4*)&Wl[j*4] = ld4(fcW + j*4);
  int cg = t & 31, cr = t >> 5;
  float4 bias = ld4(fcb + cg*4);
  float ssum[4] = {0,0,0,0}, ssq[4] = {0,0,0,0};
  for (int chunk = blockIdx.x; chunk < NCRY/16; chunk += gridDim.x){
    int c0 = chunk*16;
    __syncthreads();
    for (int j = t; j < 256; j += 512){
      int rr = j & 15, c = j >> 4;
      float4 v = ld4(crys + (size_t)(c0+rr)*64 + c*4);
      int k = c*4;
      cb[k][rr]=v.x; cb[k+1][rr]=v.y; cb[k+2][rr]=v.z; cb[k+3][rr]=v.w;
    }
    __syncthreads();
    float4 acc = bias;
    #pragma unroll 4
    for (int k=0;k<64;k++){
      float a = cb[k][cr];
      float4 w = *(float4*)&Wl[k*128 + cg*4];
      acc.x += a*w.x; acc.y += a*w.y; acc.z += a*w.z; acc.w += a*w.w;
    }
    *(float4*)&hid[(size_t)(c0+cr)*128 + cg*4] = acc;
    ssum[0]+=acc.x; ssum[1]+=acc.y; ssum[2]+=acc.z; ssum[3]+=acc.w;
    ssq[0]+=acc.x*acc.x; ssq[1]+=acc.y*acc.y; ssq[2]+=acc.z*acc.z; ssq[3]+=acc.w*acc.w;
  }
  __syncthreads();
  float* red = Wl;
  #pragma unroll
  for (int q=0;q<4;q++){ red[t*8+q] = ssum[q]; red[t*8+4+q] = ssq[q]; }
  __syncthreads();
  if (t < 128){
    int cgj = t >> 2, q = t & 3;
    float s = 0.f, sq = 0.f;
    for (int cri=0; cri<16; cri++){
      int tt = cri*32 + cgj;
      s  += red[tt*8+q];
      sq += red[tt*8+4+q];
    }
    partial[(size_t)blockIdx.x*256 + t]       = s;
    partial[(size_t)blockIdx.x*256 + 128 + t] = sq;
  }
}

__global__ __launch_bounds__(256) void out_kernel(const float* __restrict__ hid,
                                                  const float* __restrict__ scale, const float* __restrict__ shift,
                                                  const float* __restrict__ outW, const float* __restrict__ outb,
                                                  float* __restrict__ out){
  int c = blockIdx.x*4 + (threadIdx.x >> 6);
  int l = threadIdx.x & 63;
  float v = softplusf_(hid[(size_t)c*128 + l]*scale[l] + shift[l])*outW[l]
          + softplusf_(hid[(size_t)c*128 + 64 + l]*scale[64+l] + shift[64+l])*outW[64+l];
  for (int off=32; off; off >>= 1) v += __shfl_down(v, off);
  if (l == 0) out[c] = v + outb[0];
}

// ---------------------------------------------------------------- launch
extern "C" void kernel_launch(void* const* d_in, const int* in_sizes, int n_in,
                              void* d_out, int out_size, void* d_ws, size_t ws_size,
                              hipStream_t stream){
  const float* aw    = (const float*)d_in[0];
  const float* orig  = (const float*)d_in[1];
  const float* nbr   = (const float*)d_in[2];
  const int*   sidx  = (const int*)d_in[3];
  const int*   nidx  = (const int*)d_in[4];
  const int*   cry   = (const int*)d_in[5];
  const float* embW  = (const float*)d_in[6];
  const float* embB  = (const float*)d_in[7];
  const float* filtW = (const float*)d_in[8];
  const float* filtB = (const float*)d_in[9];
  const float* coreW = (const float*)d_in[10];
  const float* coreB = (const float*)d_in[11];
  const float* bnfg  = (const float*)d_in[12];
  const float* bnfb  = (const float*)d_in[13];
  const float* bncg  = (const float*)d_in[14];
  const float* bncb  = (const float*)d_in[15];
  const float* bnog  = (const float*)d_in[16];
  const float* bnob  = (const float*)d_in[17];
  const float* gW1   = (const float*)d_in[18];
  const float* gb1   = (const float*)d_in[19];
  const float* gbng  = (const float*)d_in[20];
  const float* gbnb  = (const float*)d_in[21];
  const float* gW2   = (const float*)d_in[22];
  const float* gb2   = (const float*)d_in[23];
  const float* fcW   = (const float*)d_in[24];
  const float* fcb   = (const float*)d_in[25];
  const float* fcbng = (const float*)d_in[26];
  const float* fcbnb = (const float*)d_in[27];
  const float* outW  = (const float*)d_in[28];
  const float* outb  = (const float*)d_in[29];
  float* out = (float*)d_out;

  float* ws      = (float*)d_ws;
  float* meanacc = ws;                              // N*64  (reused as hbuf after MP)
  float* cnt     = meanacc + (size_t)NATOM*64;      // N
  float* gate    = cnt     + NATOM;                 // N
  float* gmaxk   = gate    + NATOM;                 // C
  float* gsum    = gmaxk   + NCRY;                  // C
  float* crys    = gsum    + NCRY;                  // C*64
  float* hid     = crys    + (size_t)NCRY*64;       // C*128
  float* stats   = hid     + (size_t)NCRY*128;      // 256
  float* scale   = stats   + 256;                   // 128
  float* shift   = scale   + 128;                   // 128
  short* wth     = (short*)(shift + 128);           // 3*128*160 shorts
  short* wtl     = wth + 3*128*160;                 // 3*128*160 shorts
  float* partial = (float*)(wtl + 3*128*160);       // 2048*256 floats (2 MB)
  short* atom_h  = (short*)(partial + 2048*256);    // N*64 shorts
  short* atom_l  = atom_h + (size_t)NATOM*64;       // N*64 shorts
  short* nbr_h   = atom_l + (size_t)NATOM*64;       // M*32 shorts
  (void)in_sizes; (void)n_in; (void)out_size; (void)ws_size;

  // prep
  hipMemsetAsync(cnt, 0, NATOM*sizeof(float), stream);
  cnt_kernel<<<2048, 256, 0, stream>>>(sidx, cnt);
  recip_kernel<<<NATOM/256, 256, 0, stream>>>(cnt);
  wprep<<<240, 256, 0, stream>>>(filtW, coreW, wth, wtl);
  nbrprep<<<2048, 256, 0, stream>>>(nbr, nbr_h);
  embed_kernel<<<2048, 256, 0, stream>>>(orig, embW, embB, atom_h, atom_l);

  // message-passing layers
  for (int i = 0; i < 3; ++i){
    const short* wthL = wth + (size_t)i*128*160;
    const short* wtlL = wtl + (size_t)i*128*160;
    const float* bf = filtB + i*64;
    const float* bc = coreB + i*64;
    edge_mfma<0><<<2048, 256, 0, stream>>>(atom_h, atom_l, nbr_h, sidx, nidx, wthL, wtlL, bf, bc,
                                           nullptr, nullptr, partial, nullptr);
    colreduce<<<4, 256, 0, stream>>>(partial, stats, 2048, 256);
    bnfin_kernel<<<1, 64, 0, stream>>>(64, 1.0f/MEDGE, stats,    stats+128,    bnfg+i*64, bnfb+i*64, scale,    shift);
    bnfin_kernel<<<1, 64, 0, stream>>>(64, 1.0f/MEDGE, stats+64, stats+128+64, bncg+i*64, bncb+i*64, scale+64, shift+64);
    hipMemsetAsync(meanacc, 0, (size_t)NATOM*64*sizeof(float), stream);
    edge_mfma<1><<<2048, 256, 0, stream>>>(atom_h, atom_l, nbr_h, sidx, nidx, wthL, wtlL, bf, bc,
                                           scale, shift, nullptr, meanacc);
    meanbn_stats<<<2048, 256, 0, stream>>>(cnt, meanacc, partial);
    colreduce<<<2, 256, 0, stream>>>(partial, stats, 2048, 128);
    bnfin_kernel<<<1, 64, 0, stream>>>(64, 1.0f/NATOM, stats, stats+64, bnog+i*64, bnob+i*64, scale, shift);
    atom_update<<<2048, 256, 0, stream>>>(atom_h, atom_l, meanacc, cnt, scale, shift);
  }

  // gate MLP + BN + attention pooling (hbuf reuses meanacc)
  float* hbuf = meanacc;
  gate_pass1<<<NATOM/256, 256, 0, stream>>>(atom_h, atom_l, gW1, gb1, hbuf, partial);
  colreduce<<<1, 256, 0, stream>>>(partial, stats, NATOM/256, 32);
  bnfin_kernel<<<1, 16, 0, stream>>>(16, 1.0f/NATOM, stats, stats+16, gbng, gbnb, scale, shift);
  hipMemsetAsync(gmaxk, 0, NCRY*sizeof(unsigned), stream);
  gate_pass2<<<NATOM/256, 256, 0, stream>>>(hbuf, scale, shift, gW2, gb2, cry, gate, (unsigned*)gmaxk);
  hipMemsetAsync(gsum, 0, NCRY*sizeof(float), stream);
  gate_exp<<<NATOM/256, 256, 0, stream>>>(gate, aw, cry, (const unsigned*)gmaxk, gsum);
  hipMemsetAsync(crys, 0, (size_t)NCRY*64*sizeof(float), stream);
  crys_acc<<<4096, 256, 0, stream>>>(gate, gsum, cry, atom_h, atom_l, crys);

  // fc head
  fc_stats<<<1024, 512, 0, stream>>>(crys, fcW, fcb, hid, partial);
  colreduce<<<4, 256, 0, stream>>>(partial, stats, 1024, 256);
  bnfin_kernel<<<1, 128, 0, stream>>>(128, 1.0f/NCRY, stats, stats+128, fcbng, fcbnb, scale, shift);
  out_kernel<<<NCRY/4, 256, 0, stream>>>(hid, scale, shift, outW, outb, out);
}